// Round 1
// baseline (1862.460 us; speedup 1.0000x reference)
//
#include <hip/hip_runtime.h>

// FilterTopKDetections: per-class top-K over anchors.
// scores: [B, A, C] f32, boxes: [B, A, 4] f32
// out: vals [B, K, C] f32  ++  boxes_out [B, K, C, 4] f32 (flat concat)
//
// One block per (b, c). Multi-level radix-select on monotonic float key to
// find the K-th threshold, compact candidates (<=2048) into LDS with
// 64-bit key (value_key<<32 | ~anchor_idx) so sort order == jax.lax.top_k
// (descending value, ties -> lower index first), bitonic sort, emit top K.

constexpr int B_ = 8;
constexpr int A_ = 120000;
constexpr int C_ = 80;
constexpr int K_ = 1000;
constexpr int CAP = 2048;     // candidate buffer (power of 2 for bitonic)
constexpr int NTHREADS = 256;

__device__ __forceinline__ unsigned mono_key(float f) {
    unsigned bits = __float_as_uint(f);
    return (bits & 0x80000000u) ? ~bits : (bits | 0x80000000u);
}

__global__ __launch_bounds__(NTHREADS)
void topk_select_kernel(const float* __restrict__ scores,
                        const float* __restrict__ boxes,
                        float* __restrict__ out) {
    const int blk = blockIdx.x;
    const int b = blk / C_;
    const int c = blk % C_;
    const float* sc = scores + (size_t)b * A_ * C_ + c;

    __shared__ unsigned hist[4096];
    __shared__ unsigned coarse[NTHREADS];
    __shared__ unsigned long long cand[CAP];
    __shared__ unsigned s_n;
    __shared__ unsigned s_boundBin, s_boundCnt, s_aboveAdd;

    const int t = threadIdx.x;

    unsigned aboveCum = 0;   // count of keys strictly above refined prefix
    unsigned pref = 0;       // accepted high bits so far (right-aligned)
    unsigned T32 = 0;        // final 32-bit key threshold (candidates: key >= T32)

    // ---- level loop: bits[31:20] (4096 bins), [19:8] (4096), [7:0] (256) ----
    for (int lv = 0; lv < 3; ++lv) {
        const int shift = (lv == 0) ? 20 : (lv == 1) ? 8 : 0;
        const int nb = (lv == 2) ? 256 : 4096;

        for (int i = t; i < nb; i += NTHREADS) hist[i] = 0;
        __syncthreads();

        for (int a = t; a < A_; a += NTHREADS) {
            unsigned key = mono_key(sc[(size_t)a * C_]);
            bool ok = (lv == 0) ||
                      (lv == 1 ? ((key >> 20) == pref)
                               : ((key >> 8) == pref));
            if (ok) atomicAdd(&hist[(key >> shift) & (nb - 1)], 1u);
        }
        __syncthreads();

        // boundary find: highest bin where cumulative-from-top >= K - aboveCum
        const int chunk = nb / NTHREADS;   // 16 or 1
        {
            unsigned s = 0;
            for (int i = 0; i < chunk; ++i) s += hist[t * chunk + i];
            coarse[t] = s;
        }
        __syncthreads();
        if (t == 0) {
            const unsigned target = K_ - aboveCum;
            unsigned run = 0;
            int cb = NTHREADS - 1;
            for (; cb > 0; --cb) {
                if (run + coarse[cb] >= target) break;
                run += coarse[cb];
            }
            int bin = cb * chunk + (chunk - 1);
            for (; bin > cb * chunk; --bin) {
                if (run + hist[bin] >= target) break;
                run += hist[bin];
            }
            s_boundBin = (unsigned)bin;
            s_boundCnt = hist[bin];
            s_aboveAdd = run;
        }
        __syncthreads();
        const unsigned bin = s_boundBin, bc = s_boundCnt, addAbove = s_aboveAdd;
        __syncthreads();   // all reads of hist/s_* done before next level zeroes

        aboveCum += addAbove;
        pref = (lv == 0) ? bin
             : (lv == 1) ? ((pref << 12) | bin)
                         : ((pref << 8) | bin);
        const unsigned candCnt = aboveCum + bc;
        if (candCnt <= (unsigned)CAP || lv == 2) {
            T32 = (lv == 0) ? (pref << 20)
                : (lv == 1) ? (pref << 8)
                            : pref;
            break;
        }
    }

    // ---- compact candidates: key >= T32 ----
    if (t == 0) s_n = 0;
    __syncthreads();
    for (int a = t; a < A_; a += NTHREADS) {
        unsigned key = mono_key(sc[(size_t)a * C_]);
        if (key >= T32) {
            unsigned slot = atomicAdd(&s_n, 1u);
            if (slot < (unsigned)CAP) {
                // low word ~a: larger value <=> smaller index -> desc sort
                // yields ascending index among equal values (jax tie rule)
                cand[slot] = ((unsigned long long)key << 32) | (unsigned)(~(unsigned)a);
            }
        }
    }
    __syncthreads();
    const unsigned n = (s_n < (unsigned)CAP) ? s_n : (unsigned)CAP;
    for (int i = (int)n + t; i < CAP; i += NTHREADS) cand[i] = 0ull;
    __syncthreads();

    // ---- bitonic sort CAP elements, descending ----
    for (unsigned kk = 2; kk <= (unsigned)CAP; kk <<= 1) {
        for (unsigned j = kk >> 1; j > 0; j >>= 1) {
            __syncthreads();
            for (int i = t; i < CAP; i += NTHREADS) {
                const int ixj = i ^ (int)j;
                if (ixj > i) {
                    const bool up = ((i & kk) == 0);  // up segment: keep larger at i
                    unsigned long long x = cand[i], y = cand[ixj];
                    if ((x < y) == up) { cand[i] = y; cand[ixj] = x; }
                }
            }
        }
    }
    __syncthreads();

    // ---- emit top K ----
    float* vals_out = out;                              // [B, K, C]
    float* boxes_out = out + (size_t)B_ * K_ * C_;      // [B, K, C, 4]
    const float4* bx = (const float4*)(boxes + (size_t)b * A_ * 4);
    for (int kk = t; kk < K_; kk += NTHREADS) {
        const unsigned long long e = cand[kk];
        const unsigned key = (unsigned)(e >> 32);
        const unsigned aidx = ~(unsigned)e;
        const unsigned bitsv = (key & 0x80000000u) ? (key ^ 0x80000000u) : ~key;
        vals_out[((size_t)b * K_ + kk) * C_ + c] = __uint_as_float(bitsv);
        const float4 bb = bx[aidx];
        *(float4*)&boxes_out[(((size_t)b * K_ + kk) * C_ + c) * 4] = bb;
    }
}

extern "C" void kernel_launch(void* const* d_in, const int* in_sizes, int n_in,
                              void* d_out, int out_size, void* d_ws, size_t ws_size,
                              hipStream_t stream) {
    const float* scores = (const float*)d_in[0];
    const float* boxes  = (const float*)d_in[1];
    float* out = (float*)d_out;
    hipLaunchKernelGGL(topk_select_kernel, dim3(B_ * C_), dim3(NTHREADS), 0, stream,
                       scores, boxes, out);
}

// Round 2
// 803.005 us; speedup vs baseline: 2.3194x; 2.3194x over previous
//
#include <hip/hip_runtime.h>

// FilterTopKDetections: per-class top-K over anchors.
// scores: [B, A, C] f32 (uniform [0,1)), boxes: [B, A, 4] f32
// out: vals [B, K, C] f32 ++ boxes_out [B, K, C, 4] f32 (flat concat)
//
// Pipeline (all passes over scores fully coalesced):
//  K1: per-slab LDS histogram, 80 classes x 128 linear bins (bin=floor(v*128),
//      monotonic in v), flushed to global hists via packed u64 atomics.
//  K2: per-(b,c) suffix scan of 128-bin hist -> threshold bin + exact count.
//  K3: coalesced compaction of candidates (bin >= T) into global buffers,
//      64-bit sort key = mono_key(v)<<32 | ~anchor  (desc sort == jax.lax.top_k
//      order incl. tie rule: equal values -> lower index first).
//  K4: per-(b,c) bitonic sort of <=4096 candidates in LDS, emit top K vals +
//      float4 box gather. Fallback to full strided radix-select if candidates
//      overflow (never on this dataset) or ws too small.

constexpr int B_ = 8;
constexpr int A_ = 120000;
constexpr int C_ = 80;
constexpr int K_ = 1000;
constexpr int NTHREADS = 256;

constexpr int S_ = 120;            // anchor slices per batch
constexpr int ROWS = A_ / S_;      // 1000 anchors per slab
constexpr int BINS = 128;
constexpr int CAP = 4096;          // candidate cap (power of 2 for bitonic)

// ws layout
constexpr size_t GH_OFF = 0;                                    // u64 [B*C][BINS/2]
constexpr size_t GH_BYTES = (size_t)B_ * C_ * (BINS / 2) * 8;   // 327,680
constexpr size_t GCNT_OFF = GH_OFF + GH_BYTES;                  // u32 [B*C]
constexpr size_t GCNT_BYTES = (size_t)B_ * C_ * 4;              // 2,560
constexpr size_t ZERO_BYTES = GCNT_OFF + GCNT_BYTES - GH_OFF;   // memset span
constexpr size_t TINFO_OFF = GCNT_OFF + GCNT_BYTES;             // int2 [B*C]
constexpr size_t TINFO_BYTES = (size_t)B_ * C_ * 8;             // 5,120
constexpr size_t GCAND_OFF = (TINFO_OFF + TINFO_BYTES + 15) & ~(size_t)15;
constexpr size_t GCAND_BYTES = (size_t)B_ * C_ * CAP * 8;       // 20,971,520
constexpr size_t WS_NEED = GCAND_OFF + GCAND_BYTES;

__device__ __forceinline__ unsigned mono_key(float f) {
    unsigned bits = __float_as_uint(f);
    return (bits & 0x80000000u) ? ~bits : (bits | 0x80000000u);
}
__device__ __forceinline__ int lin_bin(float v) {
    // monotonic map; NaN -> 0 (no NaN in this dataset)
    if (!(v > 0.0f)) return 0;
    if (v >= 1.0f) return BINS - 1;
    return (int)(v * (float)BINS);
}

// ---------------- K1: coalesced histogram ----------------
__global__ __launch_bounds__(NTHREADS)
void hist_kernel(const float* __restrict__ scores, unsigned long long* __restrict__ gh) {
    const int b = blockIdx.x / S_;
    const int s = blockIdx.x % S_;
    __shared__ unsigned lh[C_ * BINS];          // 40 KB
    const int t = threadIdx.x;
    for (int i = t; i < C_ * BINS; i += NTHREADS) lh[i] = 0;
    __syncthreads();

    const float4* slab = (const float4*)(scores + ((size_t)b * A_ + (size_t)s * ROWS) * C_);
    const int nvec = ROWS * C_ / 4;             // 20000
    for (int i = t; i < nvec; i += NTHREADS) {
        float4 v = slab[i];
        int c0 = (i * 4) % C_;
        atomicAdd(&lh[(c0 + 0) * BINS + lin_bin(v.x)], 1u);
        atomicAdd(&lh[(c0 + 1) * BINS + lin_bin(v.y)], 1u);
        atomicAdd(&lh[(c0 + 2) * BINS + lin_bin(v.z)], 1u);
        atomicAdd(&lh[(c0 + 3) * BINS + lin_bin(v.w)], 1u);
    }
    __syncthreads();

    // flush: pack two adjacent bins into one u64 atomic (lo sums < 2^32, no carry)
    unsigned long long* ghb = gh + (size_t)b * C_ * (BINS / 2);
    for (int w = t; w < C_ * (BINS / 2); w += NTHREADS) {
        int c = w / (BINS / 2), i = w % (BINS / 2);
        unsigned long long val = (unsigned long long)lh[c * BINS + 2 * i] |
                                 ((unsigned long long)lh[c * BINS + 2 * i + 1] << 32);
        if (val) atomicAdd(&ghb[w], val);
    }
}

// ---------------- K2: threshold per (b,c) ----------------
__global__ __launch_bounds__(64)
void thresh_kernel(const unsigned long long* __restrict__ gh, int2* __restrict__ tinfo) {
    const int bc = blockIdx.x * 64 + threadIdx.x;
    if (bc >= B_ * C_) return;
    const unsigned* h = (const unsigned*)(gh + (size_t)bc * (BINS / 2));  // u32 view, 128 bins
    unsigned run = 0;
    int tb = 0;
    for (int bin = BINS - 1; bin >= 0; --bin) {
        run += h[bin];
        if (run >= (unsigned)K_) { tb = bin; break; }
    }
    tinfo[bc] = make_int2(tb, (int)run);
}

// ---------------- K3: coalesced compaction ----------------
__global__ __launch_bounds__(NTHREADS)
void compact_kernel(const float* __restrict__ scores, const int2* __restrict__ tinfo,
                    unsigned* __restrict__ gcount, unsigned long long* __restrict__ gcand) {
    const int b = blockIdx.x / S_;
    const int s = blockIdx.x % S_;
    __shared__ int tb[C_];
    const int t = threadIdx.x;
    if (t < C_) tb[t] = tinfo[b * C_ + t].x;
    __syncthreads();

    const float4* slab = (const float4*)(scores + ((size_t)b * A_ + (size_t)s * ROWS) * C_);
    const int nvec = ROWS * C_ / 4;
    for (int i = t; i < nvec; i += NTHREADS) {
        float4 v = slab[i];
        const int j = i * 4;
        const int c0 = j % C_;
        const unsigned a = (unsigned)(s * ROWS + j / C_);
        const float vv[4] = {v.x, v.y, v.z, v.w};
        #pragma unroll
        for (int e = 0; e < 4; ++e) {
            const int c = c0 + e;
            if (lin_bin(vv[e]) >= tb[c]) {
                const int bc = b * C_ + c;
                unsigned slot = atomicAdd(&gcount[bc], 1u);
                if (slot < (unsigned)CAP)
                    gcand[(size_t)bc * CAP + slot] =
                        ((unsigned long long)mono_key(vv[e]) << 32) | (unsigned)(~a);
            }
        }
    }
}

// ---------------- K4: sort + emit ----------------
__global__ __launch_bounds__(NTHREADS)
void sort_emit_kernel(const float* __restrict__ scores, const float* __restrict__ boxes,
                      const int2* __restrict__ tinfo,
                      const unsigned long long* __restrict__ gcand,
                      float* __restrict__ out) {
    const int bc = blockIdx.x;
    const int b = bc / C_;
    const int c = bc % C_;
    const int t = threadIdx.x;

    __shared__ unsigned long long cand[CAP];    // 32 KB
    __shared__ unsigned hist[4096];             // 16 KB (fallback only)
    __shared__ unsigned coarse[NTHREADS];
    __shared__ unsigned s_n;
    __shared__ unsigned s_boundBin, s_boundCnt, s_aboveAdd;

    const unsigned n_exact = (unsigned)tinfo[bc].y;

    if (n_exact <= (unsigned)CAP) {
        // ---- fast path: load precompacted candidates ----
        const unsigned long long* src = gcand + (size_t)bc * CAP;
        for (int i = t; i < CAP; i += NTHREADS)
            cand[i] = (i < (int)n_exact) ? src[i] : 0ull;
        __syncthreads();
    } else {
        // ---- fallback: full strided 3-level radix select (generic data only) ----
        const float* sc = scores + (size_t)b * A_ * C_ + c;
        unsigned aboveCum = 0, pref = 0, T32 = 0;
        for (int lv = 0; lv < 3; ++lv) {
            const int shift = (lv == 0) ? 20 : (lv == 1) ? 8 : 0;
            const int nb = (lv == 2) ? 256 : 4096;
            for (int i = t; i < nb; i += NTHREADS) hist[i] = 0;
            __syncthreads();
            for (int a = t; a < A_; a += NTHREADS) {
                unsigned key = mono_key(sc[(size_t)a * C_]);
                bool ok = (lv == 0) || (lv == 1 ? ((key >> 20) == pref) : ((key >> 8) == pref));
                if (ok) atomicAdd(&hist[(key >> shift) & (nb - 1)], 1u);
            }
            __syncthreads();
            const int chunk = nb / NTHREADS;
            {
                unsigned ssum = 0;
                for (int i = 0; i < chunk; ++i) ssum += hist[t * chunk + i];
                coarse[t] = ssum;
            }
            __syncthreads();
            if (t == 0) {
                const unsigned target = K_ - aboveCum;
                unsigned run = 0;
                int cb = NTHREADS - 1;
                for (; cb > 0; --cb) {
                    if (run + coarse[cb] >= target) break;
                    run += coarse[cb];
                }
                int bin = cb * chunk + (chunk - 1);
                for (; bin > cb * chunk; --bin) {
                    if (run + hist[bin] >= target) break;
                    run += hist[bin];
                }
                s_boundBin = (unsigned)bin; s_boundCnt = hist[bin]; s_aboveAdd = run;
            }
            __syncthreads();
            const unsigned bin = s_boundBin, bcn = s_boundCnt, addAbove = s_aboveAdd;
            __syncthreads();
            aboveCum += addAbove;
            pref = (lv == 0) ? bin : (lv == 1) ? ((pref << 12) | bin) : ((pref << 8) | bin);
            if (aboveCum + bcn <= (unsigned)CAP || lv == 2) {
                T32 = (lv == 0) ? (pref << 20) : (lv == 1) ? (pref << 8) : pref;
                break;
            }
        }
        if (t == 0) s_n = 0;
        __syncthreads();
        for (int a = t; a < A_; a += NTHREADS) {
            unsigned key = mono_key(sc[(size_t)a * C_]);
            if (key >= T32) {
                unsigned slot = atomicAdd(&s_n, 1u);
                if (slot < (unsigned)CAP)
                    cand[slot] = ((unsigned long long)key << 32) | (unsigned)(~(unsigned)a);
            }
        }
        __syncthreads();
        const unsigned n = (s_n < (unsigned)CAP) ? s_n : (unsigned)CAP;
        for (int i = (int)n + t; i < CAP; i += NTHREADS) cand[i] = 0ull;
        __syncthreads();
    }

    // ---- bitonic sort CAP elements, descending ----
    for (unsigned kk = 2; kk <= (unsigned)CAP; kk <<= 1) {
        for (unsigned j = kk >> 1; j > 0; j >>= 1) {
            __syncthreads();
            for (int i = t; i < CAP; i += NTHREADS) {
                const int ixj = i ^ (int)j;
                if (ixj > i) {
                    const bool up = ((i & kk) == 0);
                    unsigned long long x = cand[i], y = cand[ixj];
                    if ((x < y) == up) { cand[i] = y; cand[ixj] = x; }
                }
            }
        }
    }
    __syncthreads();

    // ---- emit top K ----
    float* vals_out = out;                              // [B, K, C]
    float* boxes_out = out + (size_t)B_ * K_ * C_;      // [B, K, C, 4]
    const float4* bx = (const float4*)(boxes + (size_t)b * A_ * 4);
    for (int kk = t; kk < K_; kk += NTHREADS) {
        const unsigned long long e = cand[kk];
        const unsigned key = (unsigned)(e >> 32);
        const unsigned aidx = ~(unsigned)e;
        const unsigned bitsv = (key & 0x80000000u) ? (key ^ 0x80000000u) : ~key;
        vals_out[((size_t)b * K_ + kk) * C_ + c] = __uint_as_float(bitsv);
        const float4 bb = bx[aidx];
        *(float4*)&boxes_out[(((size_t)b * K_ + kk) * C_ + c) * 4] = bb;
    }
}

// ---------------- legacy single-kernel path (ws too small) ----------------
__global__ __launch_bounds__(NTHREADS)
void topk_select_kernel(const float* __restrict__ scores,
                        const float* __restrict__ boxes,
                        float* __restrict__ out) {
    const int blk = blockIdx.x;
    const int b = blk / C_;
    const int c = blk % C_;
    const float* sc = scores + (size_t)b * A_ * C_ + c;
    constexpr int LCAP = 2048;
    __shared__ unsigned hist[4096];
    __shared__ unsigned coarse[NTHREADS];
    __shared__ unsigned long long cand[LCAP];
    __shared__ unsigned s_n, s_boundBin, s_boundCnt, s_aboveAdd;
    const int t = threadIdx.x;
    unsigned aboveCum = 0, pref = 0, T32 = 0;
    for (int lv = 0; lv < 3; ++lv) {
        const int shift = (lv == 0) ? 20 : (lv == 1) ? 8 : 0;
        const int nb = (lv == 2) ? 256 : 4096;
        for (int i = t; i < nb; i += NTHREADS) hist[i] = 0;
        __syncthreads();
        for (int a = t; a < A_; a += NTHREADS) {
            unsigned key = mono_key(sc[(size_t)a * C_]);
            bool ok = (lv == 0) || (lv == 1 ? ((key >> 20) == pref) : ((key >> 8) == pref));
            if (ok) atomicAdd(&hist[(key >> shift) & (nb - 1)], 1u);
        }
        __syncthreads();
        const int chunk = nb / NTHREADS;
        {
            unsigned ssum = 0;
            for (int i = 0; i < chunk; ++i) ssum += hist[t * chunk + i];
            coarse[t] = ssum;
        }
        __syncthreads();
        if (t == 0) {
            const unsigned target = K_ - aboveCum;
            unsigned run = 0;
            int cb = NTHREADS - 1;
            for (; cb > 0; --cb) { if (run + coarse[cb] >= target) break; run += coarse[cb]; }
            int bin = cb * chunk + (chunk - 1);
            for (; bin > cb * chunk; --bin) { if (run + hist[bin] >= target) break; run += hist[bin]; }
            s_boundBin = (unsigned)bin; s_boundCnt = hist[bin]; s_aboveAdd = run;
        }
        __syncthreads();
        const unsigned bin = s_boundBin, bcn = s_boundCnt, addAbove = s_aboveAdd;
        __syncthreads();
        aboveCum += addAbove;
        pref = (lv == 0) ? bin : (lv == 1) ? ((pref << 12) | bin) : ((pref << 8) | bin);
        if (aboveCum + bcn <= (unsigned)LCAP || lv == 2) {
            T32 = (lv == 0) ? (pref << 20) : (lv == 1) ? (pref << 8) : pref;
            break;
        }
    }
    if (t == 0) s_n = 0;
    __syncthreads();
    for (int a = t; a < A_; a += NTHREADS) {
        unsigned key = mono_key(sc[(size_t)a * C_]);
        if (key >= T32) {
            unsigned slot = atomicAdd(&s_n, 1u);
            if (slot < (unsigned)LCAP)
                cand[slot] = ((unsigned long long)key << 32) | (unsigned)(~(unsigned)a);
        }
    }
    __syncthreads();
    const unsigned n = (s_n < (unsigned)LCAP) ? s_n : (unsigned)LCAP;
    for (int i = (int)n + t; i < LCAP; i += NTHREADS) cand[i] = 0ull;
    __syncthreads();
    for (unsigned kk = 2; kk <= (unsigned)LCAP; kk <<= 1) {
        for (unsigned j = kk >> 1; j > 0; j >>= 1) {
            __syncthreads();
            for (int i = t; i < LCAP; i += NTHREADS) {
                const int ixj = i ^ (int)j;
                if (ixj > i) {
                    const bool up = ((i & kk) == 0);
                    unsigned long long x = cand[i], y = cand[ixj];
                    if ((x < y) == up) { cand[i] = y; cand[ixj] = x; }
                }
            }
        }
    }
    __syncthreads();
    float* vals_out = out;
    float* boxes_out = out + (size_t)B_ * K_ * C_;
    const float4* bx = (const float4*)(boxes + (size_t)b * A_ * 4);
    for (int kk = t; kk < K_; kk += NTHREADS) {
        const unsigned long long e = cand[kk];
        const unsigned key = (unsigned)(e >> 32);
        const unsigned aidx = ~(unsigned)e;
        const unsigned bitsv = (key & 0x80000000u) ? (key ^ 0x80000000u) : ~key;
        vals_out[((size_t)b * K_ + kk) * C_ + c] = __uint_as_float(bitsv);
        const float4 bb = bx[aidx];
        *(float4*)&boxes_out[(((size_t)b * K_ + kk) * C_ + c) * 4] = bb;
    }
}

extern "C" void kernel_launch(void* const* d_in, const int* in_sizes, int n_in,
                              void* d_out, int out_size, void* d_ws, size_t ws_size,
                              hipStream_t stream) {
    const float* scores = (const float*)d_in[0];
    const float* boxes  = (const float*)d_in[1];
    float* out = (float*)d_out;

    if (ws_size < WS_NEED) {
        hipLaunchKernelGGL(topk_select_kernel, dim3(B_ * C_), dim3(NTHREADS), 0, stream,
                           scores, boxes, out);
        return;
    }

    char* ws = (char*)d_ws;
    unsigned long long* gh = (unsigned long long*)(ws + GH_OFF);
    unsigned* gcount = (unsigned*)(ws + GCNT_OFF);
    int2* tinfo = (int2*)(ws + TINFO_OFF);
    unsigned long long* gcand = (unsigned long long*)(ws + GCAND_OFF);

    hipMemsetAsync(ws + GH_OFF, 0, ZERO_BYTES, stream);
    hipLaunchKernelGGL(hist_kernel, dim3(B_ * S_), dim3(NTHREADS), 0, stream, scores, gh);
    hipLaunchKernelGGL(thresh_kernel, dim3((B_ * C_ + 63) / 64), dim3(64), 0, stream, gh, tinfo);
    hipLaunchKernelGGL(compact_kernel, dim3(B_ * S_), dim3(NTHREADS), 0, stream,
                       scores, tinfo, gcount, gcand);
    hipLaunchKernelGGL(sort_emit_kernel, dim3(B_ * C_), dim3(NTHREADS), 0, stream,
                       scores, boxes, tinfo, gcand, out);
}

// Round 3
// 204.835 us; speedup vs baseline: 9.0925x; 3.9203x over previous
//
#include <hip/hip_runtime.h>

// FilterTopKDetections: per-class top-K over anchors.
// scores: [B, A, C] f32 (uniform [0,1)), boxes: [B, A, 4] f32
// out: vals [B, K, C] f32 ++ boxes_out [B, K, C, 4] f32 (flat concat)
//
// Single coalesced pass over scores stages all v >= CUT candidates
// (expected ~3750 per class, CAP 4096) into per-(b,c) global buffers using
// block-aggregated reservation (80 global atomics per block, not 1 per
// element). Sort kernel: per (b,c) 128-bin select -> compact ~1030 -> bitonic
// 2048 -> emit top K. Exact strided radix-select fallback if a class has
// n < K or n > CAP (generic data only; never on this dataset).
// Sort key = mono_key(v)<<32 | ~anchor: desc order == jax.lax.top_k incl.
// tie rule (equal values -> lower index first). Validated absmax 0 in R1/R2.

constexpr int B_ = 8;
constexpr int A_ = 120000;
constexpr int C_ = 80;
constexpr int K_ = 1000;
constexpr int NT = 256;

constexpr int S_ = 120;            // anchor slabs per batch
constexpr int ROWS = A_ / S_;      // 1000 anchors per slab
constexpr float CUT = 0.96875f;    // static prefilter: top 1/32 of [0,1)
constexpr float SCALE = 4096.0f;   // fine bin: (v-CUT)*4096 in [0,128)
constexpr int FB = 128;

constexpr int CAP = 4096;          // per-(b,c) candidate cap
constexpr int SCAP = 4096;         // per-block staging cap (mean 2500, 32 sigma)
constexpr int SORTN = 2048;        // bitonic sort size

// ws layout
constexpr size_t GCNT_OFF = 0;                               // u32 [B*C]
constexpr size_t GCNT_BYTES = (size_t)B_ * C_ * 4;           // 2,560
constexpr size_t GCAND_OFF = 4096;
constexpr size_t GCAND_BYTES = (size_t)B_ * C_ * CAP * 8;    // 20,971,520
constexpr size_t WS_NEED = GCAND_OFF + GCAND_BYTES;

__device__ __forceinline__ unsigned mono_key(float f) {
    unsigned bits = __float_as_uint(f);
    return (bits & 0x80000000u) ? ~bits : (bits | 0x80000000u);
}

// ---------------- K1: single-pass stage (coalesced, block-aggregated) ----------------
__global__ __launch_bounds__(NT)
void stage_kernel(const float* __restrict__ scores,
                  unsigned* __restrict__ gcount,
                  unsigned long long* __restrict__ gcand) {
    const int b = blockIdx.x / S_;
    const int s = blockIdx.x % S_;
    const int t = threadIdx.x;

    __shared__ unsigned long long st[SCAP];    // 32 KB: key<<32 | c<<17 | a
    __shared__ unsigned cnt[C_];
    __shared__ unsigned base[C_];
    __shared__ unsigned s_n;

    if (t == 0) s_n = 0;
    for (int i = t; i < C_; i += NT) cnt[i] = 0;
    __syncthreads();

    const float4* slab = (const float4*)(scores + ((size_t)b * A_ + (size_t)s * ROWS) * C_);
    const int a0 = s * ROWS;
    for (int i = t; i < ROWS * C_ / 4; i += NT) {
        float4 v = slab[i];
        const int j = 4 * i;
        const int c0 = j % C_;
        const int a = a0 + j / C_;
        const float vv[4] = {v.x, v.y, v.z, v.w};
        #pragma unroll
        for (int e = 0; e < 4; ++e) {
            if (vv[e] >= CUT) {
                const unsigned key = __float_as_uint(vv[e]) | 0x80000000u;  // v > 0
                const unsigned c = (unsigned)(c0 + e);
                unsigned slot = atomicAdd(&s_n, 1u);
                if (slot < (unsigned)SCAP) {
                    st[slot] = ((unsigned long long)key << 32) | (c << 17) | (unsigned)a;
                    atomicAdd(&cnt[c], 1u);
                } else {
                    // staging overflow (~never): direct global path, still exact
                    const int bc = b * C_ + (int)c;
                    unsigned g = atomicAdd(&gcount[bc], 1u);
                    if (g < (unsigned)CAP)
                        gcand[(size_t)bc * CAP + g] =
                            ((unsigned long long)key << 32) | (unsigned)(~(unsigned)a);
                }
            }
        }
    }
    __syncthreads();

    // reserve contiguous per-class ranges: 80 global atomics per block
    if (t < C_) {
        base[t] = cnt[t] ? atomicAdd(&gcount[b * C_ + t], cnt[t]) : 0u;
        cnt[t] = 0;   // reuse as running offset
    }
    __syncthreads();

    const unsigned n = (s_n < (unsigned)SCAP) ? s_n : (unsigned)SCAP;
    for (unsigned i = t; i < n; i += NT) {
        const unsigned long long e = st[i];
        const unsigned lo = (unsigned)e;
        const unsigned c = (lo >> 17) & 127u;
        const unsigned a = lo & 0x1FFFFu;
        const unsigned off = atomicAdd(&cnt[c], 1u);
        const unsigned pos = base[c] + off;
        const int bc = b * C_ + (int)c;
        if (pos < (unsigned)CAP)
            gcand[(size_t)bc * CAP + pos] =
                (e & 0xFFFFFFFF00000000ull) | (unsigned)(~a);
    }
}

// ---------------- K2: per-(b,c) select + sort + emit ----------------
__global__ __launch_bounds__(NT)
void sort_emit_kernel(const float* __restrict__ scores, const float* __restrict__ boxes,
                      const unsigned* __restrict__ gcount,
                      const unsigned long long* __restrict__ gcand,
                      float* __restrict__ out) {
    const int bc = blockIdx.x;
    const int b = bc / C_;
    const int c = bc % C_;
    const int t = threadIdx.x;

    __shared__ unsigned long long buf[SORTN];   // 16 KB
    __shared__ unsigned hist4k[4096];           // 16 KB (fast uses [0..127])
    __shared__ unsigned coarse[NT];
    __shared__ unsigned s_m, s_tb, s_cnt;
    __shared__ unsigned s_boundBin, s_boundCnt, s_aboveAdd;

    const unsigned n = gcount[bc];
    bool fast = (n >= (unsigned)K_ && n <= (unsigned)CAP);

    if (fast) {
        const unsigned long long* src = gcand + (size_t)bc * CAP;
        for (int i = t; i < FB; i += NT) hist4k[i] = 0;
        __syncthreads();
        for (unsigned i = t; i < n; i += NT) {
            const unsigned key = (unsigned)(src[i] >> 32);
            const float v = __uint_as_float(key & 0x7FFFFFFFu);
            int fb = (int)((v - CUT) * SCALE);
            fb = fb < 0 ? 0 : (fb > FB - 1 ? FB - 1 : fb);
            atomicAdd(&hist4k[fb], 1u);
        }
        __syncthreads();
        if (t == 0) {
            unsigned run = 0;
            int tb = 0;
            for (int i = FB - 1; i >= 0; --i) {
                run += hist4k[i];
                if (run >= (unsigned)K_) { tb = i; break; }
            }
            s_tb = (unsigned)tb; s_m = run; s_cnt = 0;
        }
        __syncthreads();
        if (s_m <= (unsigned)SORTN) {
            const int tb = (int)s_tb;
            for (unsigned i = t; i < n; i += NT) {
                const unsigned long long e = src[i];
                const unsigned key = (unsigned)(e >> 32);
                const float v = __uint_as_float(key & 0x7FFFFFFFu);
                int fb = (int)((v - CUT) * SCALE);
                fb = fb < 0 ? 0 : (fb > FB - 1 ? FB - 1 : fb);
                if (fb >= tb) buf[atomicAdd(&s_cnt, 1u)] = e;
            }
            __syncthreads();
            for (int i = (int)s_m + t; i < SORTN; i += NT) buf[i] = 0ull;
            __syncthreads();
        } else {
            fast = false;   // adversarial tie pile-up; exact fallback below
        }
    }

    if (!fast) {
        // exact strided 3-level radix select over all A anchors (generic data)
        const float* sc = scores + (size_t)b * A_ * C_ + c;
        unsigned aboveCum = 0, pref = 0, T32 = 0;
        for (int lv = 0; lv < 3; ++lv) {
            const int shift = (lv == 0) ? 20 : (lv == 1) ? 8 : 0;
            const int nb = (lv == 2) ? 256 : 4096;
            for (int i = t; i < nb; i += NT) hist4k[i] = 0;
            __syncthreads();
            for (int a = t; a < A_; a += NT) {
                unsigned key = mono_key(sc[(size_t)a * C_]);
                bool ok = (lv == 0) || (lv == 1 ? ((key >> 20) == pref) : ((key >> 8) == pref));
                if (ok) atomicAdd(&hist4k[(key >> shift) & (nb - 1)], 1u);
            }
            __syncthreads();
            const int chunk = nb / NT;
            {
                unsigned ssum = 0;
                for (int i = 0; i < chunk; ++i) ssum += hist4k[t * chunk + i];
                coarse[t] = ssum;
            }
            __syncthreads();
            if (t == 0) {
                const unsigned target = K_ - aboveCum;
                unsigned run = 0;
                int cb = NT - 1;
                for (; cb > 0; --cb) { if (run + coarse[cb] >= target) break; run += coarse[cb]; }
                int bin = cb * chunk + (chunk - 1);
                for (; bin > cb * chunk; --bin) { if (run + hist4k[bin] >= target) break; run += hist4k[bin]; }
                s_boundBin = (unsigned)bin; s_boundCnt = hist4k[bin]; s_aboveAdd = run;
            }
            __syncthreads();
            const unsigned bin = s_boundBin, bcn = s_boundCnt, addAbove = s_aboveAdd;
            __syncthreads();
            aboveCum += addAbove;
            pref = (lv == 0) ? bin : (lv == 1) ? ((pref << 12) | bin) : ((pref << 8) | bin);
            if (aboveCum + bcn <= (unsigned)SORTN || lv == 2) {
                T32 = (lv == 0) ? (pref << 20) : (lv == 1) ? (pref << 8) : pref;
                break;
            }
        }
        if (t == 0) s_cnt = 0;
        __syncthreads();
        for (int a = t; a < A_; a += NT) {
            unsigned key = mono_key(sc[(size_t)a * C_]);
            if (key >= T32) {
                unsigned slot = atomicAdd(&s_cnt, 1u);
                if (slot < (unsigned)SORTN)
                    buf[slot] = ((unsigned long long)key << 32) | (unsigned)(~(unsigned)a);
            }
        }
        __syncthreads();
        const unsigned nn = (s_cnt < (unsigned)SORTN) ? s_cnt : (unsigned)SORTN;
        for (int i = (int)nn + t; i < SORTN; i += NT) buf[i] = 0ull;
        __syncthreads();
    }

    // ---- bitonic sort SORTN elements, descending ----
    for (unsigned kk = 2; kk <= (unsigned)SORTN; kk <<= 1) {
        for (unsigned j = kk >> 1; j > 0; j >>= 1) {
            __syncthreads();
            for (int i = t; i < SORTN; i += NT) {
                const int ixj = i ^ (int)j;
                if (ixj > i) {
                    const bool up = ((i & kk) == 0);
                    unsigned long long x = buf[i], y = buf[ixj];
                    if ((x < y) == up) { buf[i] = y; buf[ixj] = x; }
                }
            }
        }
    }
    __syncthreads();

    // ---- emit top K ----
    float* vals_out = out;                              // [B, K, C]
    float* boxes_out = out + (size_t)B_ * K_ * C_;      // [B, K, C, 4]
    const float4* bx = (const float4*)(boxes + (size_t)b * A_ * 4);
    for (int kk = t; kk < K_; kk += NT) {
        const unsigned long long e = buf[kk];
        const unsigned key = (unsigned)(e >> 32);
        const unsigned aidx = ~(unsigned)e;
        const unsigned bitsv = (key & 0x80000000u) ? (key ^ 0x80000000u) : ~key;
        vals_out[((size_t)b * K_ + kk) * C_ + c] = __uint_as_float(bitsv);
        const float4 bb = bx[aidx];
        *(float4*)&boxes_out[(((size_t)b * K_ + kk) * C_ + c) * 4] = bb;
    }
}

// ---------------- legacy single-kernel path (ws too small) ----------------
__global__ __launch_bounds__(NT)
void topk_select_kernel(const float* __restrict__ scores,
                        const float* __restrict__ boxes,
                        float* __restrict__ out) {
    const int blk = blockIdx.x;
    const int b = blk / C_;
    const int c = blk % C_;
    const float* sc = scores + (size_t)b * A_ * C_ + c;
    constexpr int LCAP = 2048;
    __shared__ unsigned hist[4096];
    __shared__ unsigned coarse[NT];
    __shared__ unsigned long long cand[LCAP];
    __shared__ unsigned s_n, s_boundBin, s_boundCnt, s_aboveAdd;
    const int t = threadIdx.x;
    unsigned aboveCum = 0, pref = 0, T32 = 0;
    for (int lv = 0; lv < 3; ++lv) {
        const int shift = (lv == 0) ? 20 : (lv == 1) ? 8 : 0;
        const int nb = (lv == 2) ? 256 : 4096;
        for (int i = t; i < nb; i += NT) hist[i] = 0;
        __syncthreads();
        for (int a = t; a < A_; a += NT) {
            unsigned key = mono_key(sc[(size_t)a * C_]);
            bool ok = (lv == 0) || (lv == 1 ? ((key >> 20) == pref) : ((key >> 8) == pref));
            if (ok) atomicAdd(&hist[(key >> shift) & (nb - 1)], 1u);
        }
        __syncthreads();
        const int chunk = nb / NT;
        {
            unsigned ssum = 0;
            for (int i = 0; i < chunk; ++i) ssum += hist[t * chunk + i];
            coarse[t] = ssum;
        }
        __syncthreads();
        if (t == 0) {
            const unsigned target = K_ - aboveCum;
            unsigned run = 0;
            int cb = NT - 1;
            for (; cb > 0; --cb) { if (run + coarse[cb] >= target) break; run += coarse[cb]; }
            int bin = cb * chunk + (chunk - 1);
            for (; bin > cb * chunk; --bin) { if (run + hist[bin] >= target) break; run += hist[bin]; }
            s_boundBin = (unsigned)bin; s_boundCnt = hist[bin]; s_aboveAdd = run;
        }
        __syncthreads();
        const unsigned bin = s_boundBin, bcn = s_boundCnt, addAbove = s_aboveAdd;
        __syncthreads();
        aboveCum += addAbove;
        pref = (lv == 0) ? bin : (lv == 1) ? ((pref << 12) | bin) : ((pref << 8) | bin);
        if (aboveCum + bcn <= (unsigned)LCAP || lv == 2) {
            T32 = (lv == 0) ? (pref << 20) : (lv == 1) ? (pref << 8) : pref;
            break;
        }
    }
    if (t == 0) s_n = 0;
    __syncthreads();
    for (int a = t; a < A_; a += NT) {
        unsigned key = mono_key(sc[(size_t)a * C_]);
        if (key >= T32) {
            unsigned slot = atomicAdd(&s_n, 1u);
            if (slot < (unsigned)LCAP)
                cand[slot] = ((unsigned long long)key << 32) | (unsigned)(~(unsigned)a);
        }
    }
    __syncthreads();
    const unsigned n = (s_n < (unsigned)LCAP) ? s_n : (unsigned)LCAP;
    for (int i = (int)n + t; i < LCAP; i += NT) cand[i] = 0ull;
    __syncthreads();
    for (unsigned kk = 2; kk <= (unsigned)LCAP; kk <<= 1) {
        for (unsigned j = kk >> 1; j > 0; j >>= 1) {
            __syncthreads();
            for (int i = t; i < LCAP; i += NT) {
                const int ixj = i ^ (int)j;
                if (ixj > i) {
                    const bool up = ((i & kk) == 0);
                    unsigned long long x = cand[i], y = cand[ixj];
                    if ((x < y) == up) { cand[i] = y; cand[ixj] = x; }
                }
            }
        }
    }
    __syncthreads();
    float* vals_out = out;
    float* boxes_out = out + (size_t)B_ * K_ * C_;
    const float4* bx = (const float4*)(boxes + (size_t)b * A_ * 4);
    for (int kk = t; kk < K_; kk += NT) {
        const unsigned long long e = cand[kk];
        const unsigned key = (unsigned)(e >> 32);
        const unsigned aidx = ~(unsigned)e;
        const unsigned bitsv = (key & 0x80000000u) ? (key ^ 0x80000000u) : ~key;
        vals_out[((size_t)b * K_ + kk) * C_ + c] = __uint_as_float(bitsv);
        const float4 bb = bx[aidx];
        *(float4*)&boxes_out[(((size_t)b * K_ + kk) * C_ + c) * 4] = bb;
    }
}

extern "C" void kernel_launch(void* const* d_in, const int* in_sizes, int n_in,
                              void* d_out, int out_size, void* d_ws, size_t ws_size,
                              hipStream_t stream) {
    const float* scores = (const float*)d_in[0];
    const float* boxes  = (const float*)d_in[1];
    float* out = (float*)d_out;

    if (ws_size < WS_NEED) {
        hipLaunchKernelGGL(topk_select_kernel, dim3(B_ * C_), dim3(NT), 0, stream,
                           scores, boxes, out);
        return;
    }

    char* ws = (char*)d_ws;
    unsigned* gcount = (unsigned*)(ws + GCNT_OFF);
    unsigned long long* gcand = (unsigned long long*)(ws + GCAND_OFF);

    hipMemsetAsync(gcount, 0, GCNT_BYTES, stream);
    hipLaunchKernelGGL(stage_kernel, dim3(B_ * S_), dim3(NT), 0, stream,
                       scores, gcount, gcand);
    hipLaunchKernelGGL(sort_emit_kernel, dim3(B_ * C_), dim3(NT), 0, stream,
                       scores, boxes, gcount, gcand, out);
}

// Round 4
// 154.844 us; speedup vs baseline: 12.0280x; 1.3228x over previous
//
#include <hip/hip_runtime.h>

// FilterTopKDetections: per-class top-K over anchors.
// scores: [B, A, C] f32 (uniform [0,1)), boxes: [B, A, 4] f32
// out: vals [B, K, C] f32 ++ boxes_out [B, K, C, 4] f32 (flat concat)
//
// K1 (stage): one coalesced pass over scores; survivors (v >= CUT, ~1/32)
//   staged into per-class LDS bins (class-major), then flushed to per-(b,c)
//   global candidate buffers as contiguous runs (80 reservation atomics per
//   block). Overflow -> direct global path (exactness preserved).
// K2 (sort_emit, XCD-swizzled: blk = c*8 + b so one batch = one XCD L2):
//   per (b,c): 128-bin select on x=(v-CUT)*2^19>>7, optional 128-sub-bin
//   refine so candidate count <= 1024, compact, bitonic sort (1024 or 2048),
//   emit top-K vals + float4 box gather. Exact strided radix-select fallback
//   for generic data (n < K or overflow). Sort key = mono_key(v)<<32 | ~a:
//   desc order == jax.lax.top_k incl. tie rule. absmax 0 in R1/R2/R3.

constexpr int B_ = 8;
constexpr int A_ = 120000;
constexpr int C_ = 80;
constexpr int K_ = 1000;
constexpr int NT = 256;

constexpr int S_ = 120;            // anchor slabs per batch
constexpr int ROWS = A_ / S_;      // 1000 anchors per slab
constexpr float CUT = 0.96875f;    // static prefilter: top 1/32 of [0,1)
constexpr float XSCALE = 524288.0f;  // (v-CUT)*2^19 in [0,16384): fb=x>>7, sb=x&127
constexpr int CAP = 4096;          // per-(b,c) candidate cap
constexpr int PCAP = 60;           // per-class LDS staging slots (mean 31.25)
constexpr int SORT1 = 1024;
constexpr int SORT2 = 2048;

// ws layout
constexpr size_t GCNT_OFF = 0;                               // u32 [B*C]
constexpr size_t GCNT_BYTES = (size_t)B_ * C_ * 4;           // 2,560
constexpr size_t GCAND_OFF = 4096;
constexpr size_t GCAND_BYTES = (size_t)B_ * C_ * CAP * 8;    // 20,971,520
constexpr size_t WS_NEED = GCAND_OFF + GCAND_BYTES;

__device__ __forceinline__ unsigned mono_key(float f) {
    unsigned bits = __float_as_uint(f);
    return (bits & 0x80000000u) ? ~bits : (bits | 0x80000000u);
}
__device__ __forceinline__ int xbin(float v) {
    // exact & monotone on [CUT, 1): v-CUT is exact (Sterbenz), *2^19 exact
    int x = (int)((v - CUT) * XSCALE);
    return x < 0 ? 0 : (x > 16383 ? 16383 : x);
}

// ---------------- K1: stage (coalesced read, class-major coalesced write) ----------------
__global__ __launch_bounds__(NT)
void stage_kernel(const float* __restrict__ scores,
                  unsigned* __restrict__ gcount,
                  unsigned long long* __restrict__ gcand) {
    const int b = blockIdx.x / S_;
    const int s = blockIdx.x % S_;
    const int t = threadIdx.x;

    __shared__ unsigned long long st[C_ * PCAP];   // 38,400 B, class-major
    __shared__ unsigned cnt[C_];
    __shared__ unsigned base[C_];

    for (int i = t; i < C_; i += NT) cnt[i] = 0;
    __syncthreads();

    const float4* slab = (const float4*)(scores + ((size_t)b * A_ + (size_t)s * ROWS) * C_);
    const int a0 = s * ROWS;
    for (int i = t; i < ROWS * C_ / 4; i += NT) {
        float4 v = slab[i];
        const int j = 4 * i;
        const int c0 = j % C_;
        const unsigned a = (unsigned)(a0 + j / C_);
        const float vv[4] = {v.x, v.y, v.z, v.w};
        #pragma unroll
        for (int e = 0; e < 4; ++e) {
            if (vv[e] >= CUT) {
                const unsigned key = __float_as_uint(vv[e]) | 0x80000000u;  // v > 0
                const int c = c0 + e;
                const unsigned slot = atomicAdd(&cnt[c], 1u);
                const unsigned long long pk =
                    ((unsigned long long)key << 32) | (unsigned)(~a);
                if (slot < (unsigned)PCAP) {
                    st[c * PCAP + slot] = pk;
                } else {
                    // per-class staging overflow (~never on this data): direct path
                    const int bc = b * C_ + c;
                    const unsigned g = atomicAdd(&gcount[bc], 1u);
                    if (g < (unsigned)CAP) gcand[(size_t)bc * CAP + g] = pk;
                }
            }
        }
    }
    __syncthreads();

    // reserve contiguous per-class ranges (80 global atomics per block)
    if (t < C_) {
        const unsigned nc = cnt[t] < (unsigned)PCAP ? cnt[t] : (unsigned)PCAP;
        base[t] = nc ? atomicAdd(&gcount[b * C_ + t], nc) : 0u;
    }
    __syncthreads();

    // class-major flush -> contiguous runs in gcand
    for (int i = t; i < C_ * PCAP; i += NT) {
        const int c = i / PCAP;
        const unsigned j = (unsigned)(i % PCAP);
        const unsigned nc = cnt[c] < (unsigned)PCAP ? cnt[c] : (unsigned)PCAP;
        if (j < nc) {
            const unsigned pos = base[c] + j;
            if (pos < (unsigned)CAP)
                gcand[((size_t)(b * C_ + c)) * CAP + pos] = st[i];
        }
    }
}

// ---------------- K2: per-(b,c) select + sort + emit (XCD-swizzled) ----------------
__global__ __launch_bounds__(NT)
void sort_emit_kernel(const float* __restrict__ scores, const float* __restrict__ boxes,
                      const unsigned* __restrict__ gcount,
                      const unsigned long long* __restrict__ gcand,
                      float* __restrict__ out) {
    // blk = c*8 + b: all 80 classes of batch b land on XCD (blk % 8) == b
    const int blk = blockIdx.x;
    const int b = blk & 7;
    const int c = blk >> 3;
    const int bc = b * C_ + c;
    const int t = threadIdx.x;

    __shared__ unsigned long long buf[SORT2];   // 16 KB
    __shared__ unsigned hist4k[4096];           // 16 KB (fast path uses [0..255])
    __shared__ unsigned coarse[NT];
    __shared__ unsigned s_tb, s_m, s_mhi, s_tb2, s_m2, s_cnt;
    __shared__ unsigned s_boundBin, s_boundCnt, s_aboveAdd;

    const unsigned n = gcount[bc];
    bool fast = (n >= (unsigned)K_ && n <= (unsigned)CAP);
    int ss = SORT1;      // sort size
    int mode = 0;        // 0: fb >= tb   1: fb > tb || (fb == tb && sb >= tb2)

    if (fast) {
        const unsigned long long* src = gcand + (size_t)bc * CAP;
        for (int i = t; i < 256; i += NT) hist4k[i] = 0;
        __syncthreads();
        for (unsigned i = t; i < n; i += NT) {
            const unsigned key = (unsigned)(src[i] >> 32);
            const int x = xbin(__uint_as_float(key & 0x7FFFFFFFu));
            atomicAdd(&hist4k[x >> 7], 1u);
        }
        __syncthreads();
        if (t == 0) {
            unsigned run = 0;
            int tb = 0;
            for (int i = 127; i >= 0; --i) {
                run += hist4k[i];
                if (run >= (unsigned)K_) { tb = i; break; }
            }
            s_tb = (unsigned)tb; s_m = run; s_mhi = run - hist4k[tb]; s_cnt = 0;
        }
        __syncthreads();
        const int tb = (int)s_tb;
        const unsigned m = s_m;

        if (m > (unsigned)SORT1) {
            // refine boundary bin on sub-bits
            for (unsigned i = t; i < n; i += NT) {
                const unsigned key = (unsigned)(src[i] >> 32);
                const int x = xbin(__uint_as_float(key & 0x7FFFFFFFu));
                if ((x >> 7) == tb) atomicAdd(&hist4k[128 + (x & 127)], 1u);
            }
            __syncthreads();
            if (t == 0) {
                unsigned run = s_mhi;
                int tb2 = 0;
                for (int i = 127; i >= 0; --i) {
                    run += hist4k[128 + i];
                    if (run >= (unsigned)K_) { tb2 = i; break; }
                }
                s_tb2 = (unsigned)tb2; s_m2 = run;
            }
            __syncthreads();
            if (s_m2 <= (unsigned)SORT1)      { mode = 1; ss = SORT1; }
            else if (m <= (unsigned)SORT2)    { mode = 0; ss = SORT2; }
            else                              { fast = false; }
        }

        if (fast) {
            const int tb2 = (int)s_tb2;
            const unsigned mm = (mode == 1) ? s_m2 : s_m;
            for (unsigned i = t; i < n; i += NT) {
                const unsigned long long e = src[i];
                const unsigned key = (unsigned)(e >> 32);
                const int x = xbin(__uint_as_float(key & 0x7FFFFFFFu));
                const int fb = x >> 7;
                bool take = (mode == 0) ? (fb >= tb)
                                        : (fb > tb || (fb == tb && (x & 127) >= tb2));
                if (take) buf[atomicAdd(&s_cnt, 1u)] = e;
            }
            __syncthreads();
            for (int i = (int)mm + t; i < ss; i += NT) buf[i] = 0ull;
            __syncthreads();
        }
    }

    if (!fast) {
        // exact strided 3-level radix select over all A anchors (generic data)
        ss = SORT2;
        const float* sc = scores + (size_t)b * A_ * C_ + c;
        unsigned aboveCum = 0, pref = 0, T32 = 0;
        for (int lv = 0; lv < 3; ++lv) {
            const int shift = (lv == 0) ? 20 : (lv == 1) ? 8 : 0;
            const int nb = (lv == 2) ? 256 : 4096;
            for (int i = t; i < nb; i += NT) hist4k[i] = 0;
            __syncthreads();
            for (int a = t; a < A_; a += NT) {
                unsigned key = mono_key(sc[(size_t)a * C_]);
                bool ok = (lv == 0) || (lv == 1 ? ((key >> 20) == pref) : ((key >> 8) == pref));
                if (ok) atomicAdd(&hist4k[(key >> shift) & (nb - 1)], 1u);
            }
            __syncthreads();
            const int chunk = nb / NT;
            {
                unsigned ssum = 0;
                for (int i = 0; i < chunk; ++i) ssum += hist4k[t * chunk + i];
                coarse[t] = ssum;
            }
            __syncthreads();
            if (t == 0) {
                const unsigned target = K_ - aboveCum;
                unsigned run = 0;
                int cb = NT - 1;
                for (; cb > 0; --cb) { if (run + coarse[cb] >= target) break; run += coarse[cb]; }
                int bin = cb * chunk + (chunk - 1);
                for (; bin > cb * chunk; --bin) { if (run + hist4k[bin] >= target) break; run += hist4k[bin]; }
                s_boundBin = (unsigned)bin; s_boundCnt = hist4k[bin]; s_aboveAdd = run;
            }
            __syncthreads();
            const unsigned bin = s_boundBin, bcn = s_boundCnt, addAbove = s_aboveAdd;
            __syncthreads();
            aboveCum += addAbove;
            pref = (lv == 0) ? bin : (lv == 1) ? ((pref << 12) | bin) : ((pref << 8) | bin);
            if (aboveCum + bcn <= (unsigned)SORT2 || lv == 2) {
                T32 = (lv == 0) ? (pref << 20) : (lv == 1) ? (pref << 8) : pref;
                break;
            }
        }
        if (t == 0) s_cnt = 0;
        __syncthreads();
        for (int a = t; a < A_; a += NT) {
            unsigned key = mono_key(sc[(size_t)a * C_]);
            if (key >= T32) {
                unsigned slot = atomicAdd(&s_cnt, 1u);
                if (slot < (unsigned)SORT2)
                    buf[slot] = ((unsigned long long)key << 32) | (unsigned)(~(unsigned)a);
            }
        }
        __syncthreads();
        const unsigned nn = (s_cnt < (unsigned)SORT2) ? s_cnt : (unsigned)SORT2;
        for (int i = (int)nn + t; i < SORT2; i += NT) buf[i] = 0ull;
        __syncthreads();
    }

    // ---- bitonic sort ss elements, descending ----
    for (unsigned kk = 2; kk <= (unsigned)ss; kk <<= 1) {
        for (unsigned j = kk >> 1; j > 0; j >>= 1) {
            __syncthreads();
            for (int i = t; i < ss; i += NT) {
                const int ixj = i ^ (int)j;
                if (ixj > i) {
                    const bool up = ((i & kk) == 0);
                    unsigned long long x = buf[i], y = buf[ixj];
                    if ((x < y) == up) { buf[i] = y; buf[ixj] = x; }
                }
            }
        }
    }
    __syncthreads();

    // ---- emit top K ----
    float* vals_out = out;                              // [B, K, C]
    float* boxes_out = out + (size_t)B_ * K_ * C_;      // [B, K, C, 4]
    const float4* bx = (const float4*)(boxes + (size_t)b * A_ * 4);
    for (int kk = t; kk < K_; kk += NT) {
        const unsigned long long e = buf[kk];
        const unsigned key = (unsigned)(e >> 32);
        const unsigned aidx = ~(unsigned)e;
        const unsigned bitsv = (key & 0x80000000u) ? (key ^ 0x80000000u) : ~key;
        vals_out[((size_t)b * K_ + kk) * C_ + c] = __uint_as_float(bitsv);
        const float4 bb = bx[aidx];
        *(float4*)&boxes_out[(((size_t)b * K_ + kk) * C_ + c) * 4] = bb;
    }
}

// ---------------- legacy single-kernel path (ws too small) ----------------
__global__ __launch_bounds__(NT)
void topk_select_kernel(const float* __restrict__ scores,
                        const float* __restrict__ boxes,
                        float* __restrict__ out) {
    const int blk = blockIdx.x;
    const int b = blk / C_;
    const int c = blk % C_;
    const float* sc = scores + (size_t)b * A_ * C_ + c;
    constexpr int LCAP = 2048;
    __shared__ unsigned hist[4096];
    __shared__ unsigned coarse[NT];
    __shared__ unsigned long long cand[LCAP];
    __shared__ unsigned s_n, s_boundBin, s_boundCnt, s_aboveAdd;
    const int t = threadIdx.x;
    unsigned aboveCum = 0, pref = 0, T32 = 0;
    for (int lv = 0; lv < 3; ++lv) {
        const int shift = (lv == 0) ? 20 : (lv == 1) ? 8 : 0;
        const int nb = (lv == 2) ? 256 : 4096;
        for (int i = t; i < nb; i += NT) hist[i] = 0;
        __syncthreads();
        for (int a = t; a < A_; a += NT) {
            unsigned key = mono_key(sc[(size_t)a * C_]);
            bool ok = (lv == 0) || (lv == 1 ? ((key >> 20) == pref) : ((key >> 8) == pref));
            if (ok) atomicAdd(&hist[(key >> shift) & (nb - 1)], 1u);
        }
        __syncthreads();
        const int chunk = nb / NT;
        {
            unsigned ssum = 0;
            for (int i = 0; i < chunk; ++i) ssum += hist[t * chunk + i];
            coarse[t] = ssum;
        }
        __syncthreads();
        if (t == 0) {
            const unsigned target = K_ - aboveCum;
            unsigned run = 0;
            int cb = NT - 1;
            for (; cb > 0; --cb) { if (run + coarse[cb] >= target) break; run += coarse[cb]; }
            int bin = cb * chunk + (chunk - 1);
            for (; bin > cb * chunk; --bin) { if (run + hist[bin] >= target) break; run += hist[bin]; }
            s_boundBin = (unsigned)bin; s_boundCnt = hist[bin]; s_aboveAdd = run;
        }
        __syncthreads();
        const unsigned bin = s_boundBin, bcn = s_boundCnt, addAbove = s_aboveAdd;
        __syncthreads();
        aboveCum += addAbove;
        pref = (lv == 0) ? bin : (lv == 1) ? ((pref << 12) | bin) : ((pref << 8) | bin);
        if (aboveCum + bcn <= (unsigned)LCAP || lv == 2) {
            T32 = (lv == 0) ? (pref << 20) : (lv == 1) ? (pref << 8) : pref;
            break;
        }
    }
    if (t == 0) s_n = 0;
    __syncthreads();
    for (int a = t; a < A_; a += NT) {
        unsigned key = mono_key(sc[(size_t)a * C_]);
        if (key >= T32) {
            unsigned slot = atomicAdd(&s_n, 1u);
            if (slot < (unsigned)LCAP)
                cand[slot] = ((unsigned long long)key << 32) | (unsigned)(~(unsigned)a);
        }
    }
    __syncthreads();
    const unsigned n = (s_n < (unsigned)LCAP) ? s_n : (unsigned)LCAP;
    for (int i = (int)n + t; i < LCAP; i += NT) cand[i] = 0ull;
    __syncthreads();
    for (unsigned kk = 2; kk <= (unsigned)LCAP; kk <<= 1) {
        for (unsigned j = kk >> 1; j > 0; j >>= 1) {
            __syncthreads();
            for (int i = t; i < LCAP; i += NT) {
                const int ixj = i ^ (int)j;
                if (ixj > i) {
                    const bool up = ((i & kk) == 0);
                    unsigned long long x = cand[i], y = cand[ixj];
                    if ((x < y) == up) { cand[i] = y; cand[ixj] = x; }
                }
            }
        }
    }
    __syncthreads();
    float* vals_out = out;
    float* boxes_out = out + (size_t)B_ * K_ * C_;
    const float4* bx = (const float4*)(boxes + (size_t)b * A_ * 4);
    for (int kk = t; kk < K_; kk += NT) {
        const unsigned long long e = cand[kk];
        const unsigned key = (unsigned)(e >> 32);
        const unsigned aidx = ~(unsigned)e;
        const unsigned bitsv = (key & 0x80000000u) ? (key ^ 0x80000000u) : ~key;
        vals_out[((size_t)b * K_ + kk) * C_ + c] = __uint_as_float(bitsv);
        const float4 bb = bx[aidx];
        *(float4*)&boxes_out[(((size_t)b * K_ + kk) * C_ + c) * 4] = bb;
    }
}

extern "C" void kernel_launch(void* const* d_in, const int* in_sizes, int n_in,
                              void* d_out, int out_size, void* d_ws, size_t ws_size,
                              hipStream_t stream) {
    const float* scores = (const float*)d_in[0];
    const float* boxes  = (const float*)d_in[1];
    float* out = (float*)d_out;

    if (ws_size < WS_NEED) {
        hipLaunchKernelGGL(topk_select_kernel, dim3(B_ * C_), dim3(NT), 0, stream,
                           scores, boxes, out);
        return;
    }

    char* ws = (char*)d_ws;
    unsigned* gcount = (unsigned*)(ws + GCNT_OFF);
    unsigned long long* gcand = (unsigned long long*)(ws + GCAND_OFF);

    hipMemsetAsync(gcount, 0, GCNT_BYTES, stream);
    hipLaunchKernelGGL(stage_kernel, dim3(B_ * S_), dim3(NT), 0, stream,
                       scores, gcount, gcand);
    hipLaunchKernelGGL(sort_emit_kernel, dim3(B_ * C_), dim3(NT), 0, stream,
                       scores, boxes, gcount, gcand, out);
}

// Round 5
// 124.513 us; speedup vs baseline: 14.9580x; 1.2436x over previous
//
#include <hip/hip_runtime.h>

// FilterTopKDetections: per-class top-K over anchors.
// scores: [B, A, C] f32 (uniform [0,1)), boxes: [B, A, 4] f32
// out: vals [B, K, C] f32 ++ boxes_out [B, K, C, 4] f32 (flat concat)
//
// K1 (stage): one coalesced pass over scores; survivors (v >= CUT, ~1/96 ->
//   mean 1250/class, min-4.5sigma > K) staged into per-class LDS bins
//   (class-major), flushed to per-(b,c) global buffers as contiguous runs
//   (80 reservation atomics per block). Per-class LDS overflow -> direct
//   global path (exactness preserved). 1920 blocks, 10.9 KB LDS -> high TLP.
// K2 (sort_emit, XCD-swizzled: blk = c*8 + b so one batch = one XCD L2):
//   per (b,c): 128-bin select on x=(v-CUT)*2^20 (exact, monotone; Sterbenz),
//   compact to <=1024 (sub-bin refine / 2048 / exact strided radix-select
//   fallbacks for generic data), bitonic sort, emit top-K vals + float4 box
//   gather. Sort key = key(v)<<32 | ~anchor: desc order == jax.lax.top_k
//   incl. tie rule (equal values -> lower index first). absmax 0 R1-R4.

constexpr int B_ = 8;
constexpr int A_ = 120000;
constexpr int C_ = 80;
constexpr int K_ = 1000;
constexpr int NT = 256;

constexpr int S_ = 240;            // anchor slabs per batch
constexpr int ROWS = A_ / S_;      // 500 anchors per slab
constexpr float CUT = 0.98958333f; // ~ 1 - 1/96: survivors mean 1250/class
constexpr float XSCALE = 1048576.0f; // (v-CUT)*2^20 in [0,~10923): fb=x>>7, sb=x&127
constexpr int CAP = 2048;          // per-(b,c) candidate cap (22 sigma)
constexpr int PCAP = 16;           // per-class LDS staging slots (mean 5.2)
constexpr int SORT1 = 1024;
constexpr int SORT2 = 2048;

// ws layout
constexpr size_t GCNT_OFF = 0;                               // u32 [B*C]
constexpr size_t GCNT_BYTES = (size_t)B_ * C_ * 4;           // 2,560
constexpr size_t GCAND_OFF = 4096;
constexpr size_t GCAND_BYTES = (size_t)B_ * C_ * CAP * 8;    // 10,485,760
constexpr size_t WS_NEED = GCAND_OFF + GCAND_BYTES;

__device__ __forceinline__ unsigned mono_key(float f) {
    unsigned bits = __float_as_uint(f);
    return (bits & 0x80000000u) ? ~bits : (bits | 0x80000000u);
}
__device__ __forceinline__ int xbin(float v) {
    // exact & monotone on [CUT, 1): v-CUT exact (Sterbenz: CUT<=v<2*CUT),
    // *2^20 exact (power of two). Max x ~ 10923 < 16384.
    int x = (int)((v - CUT) * XSCALE);
    return x < 0 ? 0 : (x > 16383 ? 16383 : x);
}

// ---------------- K1: stage (coalesced read, class-major flush) ----------------
__global__ __launch_bounds__(NT)
void stage_kernel(const float* __restrict__ scores,
                  unsigned* __restrict__ gcount,
                  unsigned long long* __restrict__ gcand) {
    const int b = blockIdx.x / S_;
    const int s = blockIdx.x % S_;
    const int t = threadIdx.x;

    __shared__ unsigned long long st[C_ * PCAP];   // 10,240 B, class-major
    __shared__ unsigned cnt[C_];
    __shared__ unsigned base[C_];

    for (int i = t; i < C_; i += NT) cnt[i] = 0;
    __syncthreads();

    const float4* slab = (const float4*)(scores + ((size_t)b * A_ + (size_t)s * ROWS) * C_);
    constexpr int NVEC = ROWS * C_ / 4;            // 10000
    // incremental c0 / a: j = 4*i, c0 = j % 80, a = a0 + j / 80
    int c0 = (4 * t) % C_;
    int a  = s * ROWS + (4 * t) / C_;
    for (int i = t; i < NVEC; i += NT) {
        float4 v = slab[i];
        const float vv[4] = {v.x, v.y, v.z, v.w};
        #pragma unroll
        for (int e = 0; e < 4; ++e) {
            if (vv[e] >= CUT) {
                const unsigned key = __float_as_uint(vv[e]) | 0x80000000u;  // v > 0
                const int c = c0 + e;
                const unsigned slot = atomicAdd(&cnt[c], 1u);
                const unsigned long long pk =
                    ((unsigned long long)key << 32) | (unsigned)(~(unsigned)a);
                if (slot < (unsigned)PCAP) {
                    st[c * PCAP + slot] = pk;
                } else {
                    // per-class staging overflow (rare): direct path, still exact
                    const int bc = b * C_ + c;
                    const unsigned g = atomicAdd(&gcount[bc], 1u);
                    if (g < (unsigned)CAP) gcand[(size_t)bc * CAP + g] = pk;
                }
            }
        }
        // advance by NT float4s = 1024 elements = 12*80 + 64
        c0 += 64;
        a += 12;
        if (c0 >= C_) { c0 -= C_; a += 1; }
    }
    __syncthreads();

    // reserve contiguous per-class ranges (80 global atomics per block)
    if (t < C_) {
        const unsigned nc = cnt[t] < (unsigned)PCAP ? cnt[t] : (unsigned)PCAP;
        base[t] = nc ? atomicAdd(&gcount[b * C_ + t], nc) : 0u;
    }
    __syncthreads();

    // class-major flush -> contiguous runs in gcand
    for (int i = t; i < C_ * PCAP; i += NT) {
        const int c = i / PCAP;
        const unsigned j = (unsigned)(i % PCAP);
        const unsigned nc = cnt[c] < (unsigned)PCAP ? cnt[c] : (unsigned)PCAP;
        if (j < nc) {
            const unsigned pos = base[c] + j;
            if (pos < (unsigned)CAP)
                gcand[((size_t)(b * C_ + c)) * CAP + pos] = st[i];
        }
    }
}

// ---------------- K2: per-(b,c) select + sort + emit (XCD-swizzled) ----------------
__global__ __launch_bounds__(NT)
void sort_emit_kernel(const float* __restrict__ scores, const float* __restrict__ boxes,
                      const unsigned* __restrict__ gcount,
                      const unsigned long long* __restrict__ gcand,
                      float* __restrict__ out) {
    // blk = c*8 + b: all 80 classes of batch b land on XCD (blk % 8) == b
    const int blk = blockIdx.x;
    const int b = blk & 7;
    const int c = blk >> 3;
    const int bc = b * C_ + c;
    const int t = threadIdx.x;

    __shared__ unsigned long long buf[SORT2];   // 16 KB
    __shared__ unsigned hist4k[4096];           // 16 KB (fast path uses [0..255])
    __shared__ unsigned coarse[NT];
    __shared__ unsigned s_tb, s_m, s_mhi, s_tb2, s_m2, s_cnt;
    __shared__ unsigned s_boundBin, s_boundCnt, s_aboveAdd;

    const unsigned n = gcount[bc];
    bool fast = (n >= (unsigned)K_ && n <= (unsigned)CAP);
    int ss = SORT1;      // sort size
    int mode = 0;        // 0: fb >= tb   1: fb > tb || (fb == tb && sb >= tb2)

    if (fast) {
        const unsigned long long* src = gcand + (size_t)bc * CAP;
        for (int i = t; i < 256; i += NT) hist4k[i] = 0;
        __syncthreads();
        for (unsigned i = t; i < n; i += NT) {
            const unsigned key = (unsigned)(src[i] >> 32);
            const int x = xbin(__uint_as_float(key & 0x7FFFFFFFu));
            atomicAdd(&hist4k[x >> 7], 1u);
        }
        __syncthreads();
        if (t == 0) {
            unsigned run = 0;
            int tb = 0;
            for (int i = 127; i >= 0; --i) {
                run += hist4k[i];
                if (run >= (unsigned)K_) { tb = i; break; }
            }
            s_tb = (unsigned)tb; s_m = run; s_mhi = run - hist4k[tb]; s_cnt = 0;
        }
        __syncthreads();
        const int tb = (int)s_tb;
        const unsigned m = s_m;

        if (m > (unsigned)SORT1) {
            // refine boundary bin on sub-bits
            for (unsigned i = t; i < n; i += NT) {
                const unsigned key = (unsigned)(src[i] >> 32);
                const int x = xbin(__uint_as_float(key & 0x7FFFFFFFu));
                if ((x >> 7) == tb) atomicAdd(&hist4k[128 + (x & 127)], 1u);
            }
            __syncthreads();
            if (t == 0) {
                unsigned run = s_mhi;
                int tb2 = 0;
                for (int i = 127; i >= 0; --i) {
                    run += hist4k[128 + i];
                    if (run >= (unsigned)K_) { tb2 = i; break; }
                }
                s_tb2 = (unsigned)tb2; s_m2 = run;
            }
            __syncthreads();
            if (s_m2 <= (unsigned)SORT1)      { mode = 1; ss = SORT1; }
            else if (m <= (unsigned)SORT2)    { mode = 0; ss = SORT2; }
            else                              { fast = false; }
        }

        if (fast) {
            const int tb2 = (int)s_tb2;
            const unsigned mm = (mode == 1) ? s_m2 : s_m;
            for (unsigned i = t; i < n; i += NT) {
                const unsigned long long e = src[i];
                const unsigned key = (unsigned)(e >> 32);
                const int x = xbin(__uint_as_float(key & 0x7FFFFFFFu));
                const int fb = x >> 7;
                bool take = (mode == 0) ? (fb >= tb)
                                        : (fb > tb || (fb == tb && (x & 127) >= tb2));
                if (take) buf[atomicAdd(&s_cnt, 1u)] = e;
            }
            __syncthreads();
            for (int i = (int)mm + t; i < ss; i += NT) buf[i] = 0ull;
            __syncthreads();
        }
    }

    if (!fast) {
        // exact strided 3-level radix select over all A anchors (generic data)
        ss = SORT2;
        const float* sc = scores + (size_t)b * A_ * C_ + c;
        unsigned aboveCum = 0, pref = 0, T32 = 0;
        for (int lv = 0; lv < 3; ++lv) {
            const int shift = (lv == 0) ? 20 : (lv == 1) ? 8 : 0;
            const int nb = (lv == 2) ? 256 : 4096;
            for (int i = t; i < nb; i += NT) hist4k[i] = 0;
            __syncthreads();
            for (int a = t; a < A_; a += NT) {
                unsigned key = mono_key(sc[(size_t)a * C_]);
                bool ok = (lv == 0) || (lv == 1 ? ((key >> 20) == pref) : ((key >> 8) == pref));
                if (ok) atomicAdd(&hist4k[(key >> shift) & (nb - 1)], 1u);
            }
            __syncthreads();
            const int chunk = nb / NT;
            {
                unsigned ssum = 0;
                for (int i = 0; i < chunk; ++i) ssum += hist4k[t * chunk + i];
                coarse[t] = ssum;
            }
            __syncthreads();
            if (t == 0) {
                const unsigned target = K_ - aboveCum;
                unsigned run = 0;
                int cb = NT - 1;
                for (; cb > 0; --cb) { if (run + coarse[cb] >= target) break; run += coarse[cb]; }
                int bin = cb * chunk + (chunk - 1);
                for (; bin > cb * chunk; --bin) { if (run + hist4k[bin] >= target) break; run += hist4k[bin]; }
                s_boundBin = (unsigned)bin; s_boundCnt = hist4k[bin]; s_aboveAdd = run;
            }
            __syncthreads();
            const unsigned bin = s_boundBin, bcn = s_boundCnt, addAbove = s_aboveAdd;
            __syncthreads();
            aboveCum += addAbove;
            pref = (lv == 0) ? bin : (lv == 1) ? ((pref << 12) | bin) : ((pref << 8) | bin);
            if (aboveCum + bcn <= (unsigned)SORT2 || lv == 2) {
                T32 = (lv == 0) ? (pref << 20) : (lv == 1) ? (pref << 8) : pref;
                break;
            }
        }
        if (t == 0) s_cnt = 0;
        __syncthreads();
        for (int a = t; a < A_; a += NT) {
            unsigned key = mono_key(sc[(size_t)a * C_]);
            if (key >= T32) {
                unsigned slot = atomicAdd(&s_cnt, 1u);
                if (slot < (unsigned)SORT2)
                    buf[slot] = ((unsigned long long)key << 32) | (unsigned)(~(unsigned)a);
            }
        }
        __syncthreads();
        const unsigned nn = (s_cnt < (unsigned)SORT2) ? s_cnt : (unsigned)SORT2;
        for (int i = (int)nn + t; i < SORT2; i += NT) buf[i] = 0ull;
        __syncthreads();
    }

    // ---- bitonic sort ss elements, descending ----
    for (unsigned kk = 2; kk <= (unsigned)ss; kk <<= 1) {
        for (unsigned j = kk >> 1; j > 0; j >>= 1) {
            __syncthreads();
            for (int i = t; i < ss; i += NT) {
                const int ixj = i ^ (int)j;
                if (ixj > i) {
                    const bool up = ((i & kk) == 0);
                    unsigned long long x = buf[i], y = buf[ixj];
                    if ((x < y) == up) { buf[i] = y; buf[ixj] = x; }
                }
            }
        }
    }
    __syncthreads();

    // ---- emit top K ----
    float* vals_out = out;                              // [B, K, C]
    float* boxes_out = out + (size_t)B_ * K_ * C_;      // [B, K, C, 4]
    const float4* bx = (const float4*)(boxes + (size_t)b * A_ * 4);
    for (int kk = t; kk < K_; kk += NT) {
        const unsigned long long e = buf[kk];
        const unsigned key = (unsigned)(e >> 32);
        const unsigned aidx = ~(unsigned)e;
        const unsigned bitsv = (key & 0x80000000u) ? (key ^ 0x80000000u) : ~key;
        vals_out[((size_t)b * K_ + kk) * C_ + c] = __uint_as_float(bitsv);
        const float4 bb = bx[aidx];
        *(float4*)&boxes_out[(((size_t)b * K_ + kk) * C_ + c) * 4] = bb;
    }
}

// ---------------- legacy single-kernel path (ws too small) ----------------
__global__ __launch_bounds__(NT)
void topk_select_kernel(const float* __restrict__ scores,
                        const float* __restrict__ boxes,
                        float* __restrict__ out) {
    const int blk = blockIdx.x;
    const int b = blk / C_;
    const int c = blk % C_;
    const float* sc = scores + (size_t)b * A_ * C_ + c;
    constexpr int LCAP = 2048;
    __shared__ unsigned hist[4096];
    __shared__ unsigned coarse[NT];
    __shared__ unsigned long long cand[LCAP];
    __shared__ unsigned s_n, s_boundBin, s_boundCnt, s_aboveAdd;
    const int t = threadIdx.x;
    unsigned aboveCum = 0, pref = 0, T32 = 0;
    for (int lv = 0; lv < 3; ++lv) {
        const int shift = (lv == 0) ? 20 : (lv == 1) ? 8 : 0;
        const int nb = (lv == 2) ? 256 : 4096;
        for (int i = t; i < nb; i += NT) hist[i] = 0;
        __syncthreads();
        for (int a = t; a < A_; a += NT) {
            unsigned key = mono_key(sc[(size_t)a * C_]);
            bool ok = (lv == 0) || (lv == 1 ? ((key >> 20) == pref) : ((key >> 8) == pref));
            if (ok) atomicAdd(&hist[(key >> shift) & (nb - 1)], 1u);
        }
        __syncthreads();
        const int chunk = nb / NT;
        {
            unsigned ssum = 0;
            for (int i = 0; i < chunk; ++i) ssum += hist[t * chunk + i];
            coarse[t] = ssum;
        }
        __syncthreads();
        if (t == 0) {
            const unsigned target = K_ - aboveCum;
            unsigned run = 0;
            int cb = NT - 1;
            for (; cb > 0; --cb) { if (run + coarse[cb] >= target) break; run += coarse[cb]; }
            int bin = cb * chunk + (chunk - 1);
            for (; bin > cb * chunk; --bin) { if (run + hist[bin] >= target) break; run += hist[bin]; }
            s_boundBin = (unsigned)bin; s_boundCnt = hist[bin]; s_aboveAdd = run;
        }
        __syncthreads();
        const unsigned bin = s_boundBin, bcn = s_boundCnt, addAbove = s_aboveAdd;
        __syncthreads();
        aboveCum += addAbove;
        pref = (lv == 0) ? bin : (lv == 1) ? ((pref << 12) | bin) : ((pref << 8) | bin);
        if (aboveCum + bcn <= (unsigned)LCAP || lv == 2) {
            T32 = (lv == 0) ? (pref << 20) : (lv == 1) ? (pref << 8) : pref;
            break;
        }
    }
    if (t == 0) s_n = 0;
    __syncthreads();
    for (int a = t; a < A_; a += NT) {
        unsigned key = mono_key(sc[(size_t)a * C_]);
        if (key >= T32) {
            unsigned slot = atomicAdd(&s_n, 1u);
            if (slot < (unsigned)LCAP)
                cand[slot] = ((unsigned long long)key << 32) | (unsigned)(~(unsigned)a);
        }
    }
    __syncthreads();
    const unsigned n = (s_n < (unsigned)LCAP) ? s_n : (unsigned)LCAP;
    for (int i = (int)n + t; i < LCAP; i += NT) cand[i] = 0ull;
    __syncthreads();
    for (unsigned kk = 2; kk <= (unsigned)LCAP; kk <<= 1) {
        for (unsigned j = kk >> 1; j > 0; j >>= 1) {
            __syncthreads();
            for (int i = t; i < LCAP; i += NT) {
                const int ixj = i ^ (int)j;
                if (ixj > i) {
                    const bool up = ((i & kk) == 0);
                    unsigned long long x = cand[i], y = cand[ixj];
                    if ((x < y) == up) { cand[i] = y; cand[ixj] = x; }
                }
            }
        }
    }
    __syncthreads();
    float* vals_out = out;
    float* boxes_out = out + (size_t)B_ * K_ * C_;
    const float4* bx = (const float4*)(boxes + (size_t)b * A_ * 4);
    for (int kk = t; kk < K_; kk += NT) {
        const unsigned long long e = cand[kk];
        const unsigned key = (unsigned)(e >> 32);
        const unsigned aidx = ~(unsigned)e;
        const unsigned bitsv = (key & 0x80000000u) ? (key ^ 0x80000000u) : ~key;
        vals_out[((size_t)b * K_ + kk) * C_ + c] = __uint_as_float(bitsv);
        const float4 bb = bx[aidx];
        *(float4*)&boxes_out[(((size_t)b * K_ + kk) * C_ + c) * 4] = bb;
    }
}

extern "C" void kernel_launch(void* const* d_in, const int* in_sizes, int n_in,
                              void* d_out, int out_size, void* d_ws, size_t ws_size,
                              hipStream_t stream) {
    const float* scores = (const float*)d_in[0];
    const float* boxes  = (const float*)d_in[1];
    float* out = (float*)d_out;

    if (ws_size < WS_NEED) {
        hipLaunchKernelGGL(topk_select_kernel, dim3(B_ * C_), dim3(NT), 0, stream,
                           scores, boxes, out);
        return;
    }

    char* ws = (char*)d_ws;
    unsigned* gcount = (unsigned*)(ws + GCNT_OFF);
    unsigned long long* gcand = (unsigned long long*)(ws + GCAND_OFF);

    hipMemsetAsync(gcount, 0, GCNT_BYTES, stream);
    hipLaunchKernelGGL(stage_kernel, dim3(B_ * S_), dim3(NT), 0, stream,
                       scores, gcount, gcand);
    hipLaunchKernelGGL(sort_emit_kernel, dim3(B_ * C_), dim3(NT), 0, stream,
                       scores, boxes, gcount, gcand, out);
}

// Round 6
// 103.206 us; speedup vs baseline: 18.0461x; 1.2065x over previous
//
#include <hip/hip_runtime.h>

// FilterTopKDetections: per-class top-K over anchors.
// scores: [B, A, C] f32 (uniform [0,1)), boxes: [B, A, 4] f32
// out: vals [B, K, C] f32 ++ boxes_out [B, K, C, 4] f32 (flat concat)
//
// K1 (stage, 256 thr): one coalesced pass over scores; survivors (v >= CUT,
//   ~1/96 -> mean 1250/class) staged into per-class LDS bins (class-major),
//   flushed to per-(b,c) global buffers as contiguous runs (80 reservation
//   atomics per block). Per-class LDS overflow -> direct global path
//   (exactness preserved). Loads software-pipelined.
// K2 (sort_emit, 512 thr, XCD-swizzled blk = c*8 + b -> one batch per XCD L2):
//   per (b,c): 128-bin select on x=(v-CUT)*2^20 (exact, monotone; Sterbenz),
//   PARALLEL suffix-scan + boundary detect (no serial t==0 scans on the fast
//   path), compact to <=1024 (sub-bin refine / 2048 / exact strided
//   radix-select fallbacks), bitonic sort, emit top-K vals + float4 boxes.
//   Sort key = key(v)<<32 | ~anchor: desc order == jax.lax.top_k incl. tie
//   rule (equal values -> lower index first). absmax 0 R1-R5.

constexpr int B_ = 8;
constexpr int A_ = 120000;
constexpr int C_ = 80;
constexpr int K_ = 1000;
constexpr int NT = 256;    // stage / legacy
constexpr int NT2 = 512;   // sort_emit

constexpr int S_ = 240;            // anchor slabs per batch
constexpr int ROWS = A_ / S_;      // 500 anchors per slab
constexpr float CUT = 0.98958333f; // ~ 1 - 1/96: survivors mean 1250/class
constexpr float XSCALE = 1048576.0f; // (v-CUT)*2^20 in [0,~10923)
constexpr int CAP = 2048;          // per-(b,c) candidate cap (22 sigma)
constexpr int PCAP = 16;           // per-class LDS staging slots (mean 5.2)
constexpr int SORT1 = 1024;
constexpr int SORT2 = 2048;

// ws layout
constexpr size_t GCNT_OFF = 0;                               // u32 [B*C]
constexpr size_t GCNT_BYTES = (size_t)B_ * C_ * 4;           // 2,560
constexpr size_t GCAND_OFF = 4096;
constexpr size_t GCAND_BYTES = (size_t)B_ * C_ * CAP * 8;    // 10,485,760
constexpr size_t WS_NEED = GCAND_OFF + GCAND_BYTES;

__device__ __forceinline__ unsigned mono_key(float f) {
    unsigned bits = __float_as_uint(f);
    return (bits & 0x80000000u) ? ~bits : (bits | 0x80000000u);
}
__device__ __forceinline__ int xbin(float v) {
    // exact & monotone on [CUT, 1): v-CUT exact (Sterbenz: CUT<=v<2*CUT),
    // *2^20 exact (power of two). Max x ~ 10923 < 16384.
    int x = (int)((v - CUT) * XSCALE);
    return x < 0 ? 0 : (x > 16383 ? 16383 : x);
}

// ---------------- K1: stage (coalesced read, class-major flush) ----------------
__global__ __launch_bounds__(NT)
void stage_kernel(const float* __restrict__ scores,
                  unsigned* __restrict__ gcount,
                  unsigned long long* __restrict__ gcand) {
    const int b = blockIdx.x / S_;
    const int s = blockIdx.x % S_;
    const int t = threadIdx.x;

    __shared__ unsigned long long st[C_ * PCAP];   // 10,240 B, class-major
    __shared__ unsigned cnt[C_];
    __shared__ unsigned base[C_];

    for (int i = t; i < C_; i += NT) cnt[i] = 0;
    __syncthreads();

    const float4* slab = (const float4*)(scores + ((size_t)b * A_ + (size_t)s * ROWS) * C_);
    constexpr int NVEC = ROWS * C_ / 4;            // 10000
    // incremental c0 / a: j = 4*i, c0 = j % 80, a = a0 + j / 80
    int c0 = (4 * t) % C_;
    int a  = s * ROWS + (4 * t) / C_;
    int i = t;
    float4 v = make_float4(0.f, 0.f, 0.f, 0.f);
    if (i < NVEC) v = slab[i];
    while (i < NVEC) {
        const int in = i + NT;
        float4 vn = v;
        if (in < NVEC) vn = slab[in];              // prefetch next iteration
        const float vv[4] = {v.x, v.y, v.z, v.w};
        #pragma unroll
        for (int e = 0; e < 4; ++e) {
            if (vv[e] >= CUT) {
                const unsigned key = __float_as_uint(vv[e]) | 0x80000000u;  // v > 0
                const int c = c0 + e;
                const unsigned slot = atomicAdd(&cnt[c], 1u);
                const unsigned long long pk =
                    ((unsigned long long)key << 32) | (unsigned)(~(unsigned)a);
                if (slot < (unsigned)PCAP) {
                    st[c * PCAP + slot] = pk;
                } else {
                    // per-class staging overflow (rare): direct path, still exact
                    const int bc = b * C_ + c;
                    const unsigned g = atomicAdd(&gcount[bc], 1u);
                    if (g < (unsigned)CAP) gcand[(size_t)bc * CAP + g] = pk;
                }
            }
        }
        // advance by NT float4s = 1024 elements = 12*80 + 64
        c0 += 64;
        a += 12;
        if (c0 >= C_) { c0 -= C_; a += 1; }
        i = in;
        v = vn;
    }
    __syncthreads();

    // reserve contiguous per-class ranges (80 global atomics per block)
    if (t < C_) {
        const unsigned nc = cnt[t] < (unsigned)PCAP ? cnt[t] : (unsigned)PCAP;
        base[t] = nc ? atomicAdd(&gcount[b * C_ + t], nc) : 0u;
    }
    __syncthreads();

    // class-major flush -> contiguous runs in gcand
    for (int i2 = t; i2 < C_ * PCAP; i2 += NT) {
        const int c = i2 / PCAP;
        const unsigned j = (unsigned)(i2 % PCAP);
        const unsigned nc = cnt[c] < (unsigned)PCAP ? cnt[c] : (unsigned)PCAP;
        if (j < nc) {
            const unsigned pos = base[c] + j;
            if (pos < (unsigned)CAP)
                gcand[((size_t)(b * C_ + c)) * CAP + pos] = st[i2];
        }
    }
}

// ---------------- K2: per-(b,c) select + sort + emit (XCD-swizzled, 512 thr) ----------------
__global__ __launch_bounds__(NT2)
void sort_emit_kernel(const float* __restrict__ scores, const float* __restrict__ boxes,
                      const unsigned* __restrict__ gcount,
                      const unsigned long long* __restrict__ gcand,
                      float* __restrict__ out) {
    // blk = c*8 + b: all 80 classes of batch b land on XCD (blk % 8) == b
    const int blk = blockIdx.x;
    const int b = blk & 7;
    const int c = blk >> 3;
    const int bc = b * C_ + c;
    const int t = threadIdx.x;

    __shared__ unsigned long long buf[SORT2];   // 16 KB
    __shared__ unsigned hist4k[4096];           // 16 KB (fast path uses [0..255])
    __shared__ unsigned coarse[NT2];
    __shared__ unsigned s_tb, s_m, s_mhi, s_tb2, s_m2, s_cnt;
    __shared__ unsigned s_boundBin, s_boundCnt, s_aboveAdd;

    const unsigned n = gcount[bc];
    bool fast = (n >= (unsigned)K_ && n <= (unsigned)CAP);
    int ss = SORT1;      // sort size
    int mode = 0;        // 0: fb >= tb   1: fb > tb || (fb == tb && sb >= tb2)

    if (fast) {
        const unsigned long long* src = gcand + (size_t)bc * CAP;
        for (int i = t; i < 256; i += NT2) hist4k[i] = 0;
        __syncthreads();
        for (unsigned i = t; i < n; i += NT2) {
            const unsigned key = (unsigned)(src[i] >> 32);
            const int x = xbin(__uint_as_float(key & 0x7FFFFFFFu));
            atomicAdd(&hist4k[x >> 7], 1u);
        }
        __syncthreads();
        // parallel suffix-scan of hist4k[0..127] (in place, Hillis-Steele)
        for (int d = 1; d < 128; d <<= 1) {
            unsigned add = 0;
            if (t < 128 && t + d < 128) add = hist4k[t + d];
            __syncthreads();
            if (t < 128) hist4k[t] += add;
            __syncthreads();
        }
        // boundary detect: largest tb with sfx[tb] >= K (exists: sfx[0]=n>=K)
        if (t < 128) {
            const unsigned si = hist4k[t];
            const unsigned snext = (t < 127) ? hist4k[t + 1] : 0u;
            if (si >= (unsigned)K_ && snext < (unsigned)K_) {
                s_tb = (unsigned)t; s_m = si; s_mhi = snext;
            }
        }
        if (t == 0) s_cnt = 0;
        __syncthreads();
        const int tb = (int)s_tb;
        const unsigned m = s_m;

        if (m > (unsigned)SORT1) {
            // refine boundary bin on sub-bits (hist4k[128..255] still zero)
            for (unsigned i = t; i < n; i += NT2) {
                const unsigned key = (unsigned)(src[i] >> 32);
                const int x = xbin(__uint_as_float(key & 0x7FFFFFFFu));
                if ((x >> 7) == tb) atomicAdd(&hist4k[128 + (x & 127)], 1u);
            }
            __syncthreads();
            for (int d = 1; d < 128; d <<= 1) {
                unsigned add = 0;
                if (t < 128 && t + d < 128) add = hist4k[128 + t + d];
                __syncthreads();
                if (t < 128) hist4k[128 + t] += add;
                __syncthreads();
            }
            if (t < 128) {
                const unsigned si = s_mhi + hist4k[128 + t];
                const unsigned snext = s_mhi + ((t < 127) ? hist4k[128 + t + 1] : 0u);
                if (si >= (unsigned)K_ && snext < (unsigned)K_) {
                    s_tb2 = (unsigned)t; s_m2 = si;
                }
            }
            __syncthreads();
            if (s_m2 <= (unsigned)SORT1)      { mode = 1; ss = SORT1; }
            else if (m <= (unsigned)SORT2)    { mode = 0; ss = SORT2; }
            else                              { fast = false; }
        }

        if (fast) {
            const int tb2 = (int)s_tb2;
            const unsigned mm = (mode == 1) ? s_m2 : s_m;
            for (unsigned i = t; i < n; i += NT2) {
                const unsigned long long e = src[i];
                const unsigned key = (unsigned)(e >> 32);
                const int x = xbin(__uint_as_float(key & 0x7FFFFFFFu));
                const int fb = x >> 7;
                bool take = (mode == 0) ? (fb >= tb)
                                        : (fb > tb || (fb == tb && (x & 127) >= tb2));
                if (take) buf[atomicAdd(&s_cnt, 1u)] = e;
            }
            __syncthreads();
            for (int i = (int)mm + t; i < ss; i += NT2) buf[i] = 0ull;
            __syncthreads();
        }
    }

    if (!fast) {
        // exact strided 3-level radix select over all A anchors (generic data)
        ss = SORT2;
        const float* sc = scores + (size_t)b * A_ * C_ + c;
        unsigned aboveCum = 0, pref = 0, T32 = 0;
        for (int lv = 0; lv < 3; ++lv) {
            const int shift = (lv == 0) ? 20 : (lv == 1) ? 8 : 0;
            const int nb = (lv == 2) ? 256 : 4096;
            for (int i = t; i < nb; i += NT2) hist4k[i] = 0;
            __syncthreads();
            for (int a = t; a < A_; a += NT2) {
                unsigned key = mono_key(sc[(size_t)a * C_]);
                bool ok = (lv == 0) || (lv == 1 ? ((key >> 20) == pref) : ((key >> 8) == pref));
                if (ok) atomicAdd(&hist4k[(key >> shift) & (nb - 1)], 1u);
            }
            __syncthreads();
            const int active = (nb < NT2) ? nb : NT2;
            const int chunk = nb / active;
            if (t < active) {
                unsigned ssum = 0;
                for (int i = 0; i < chunk; ++i) ssum += hist4k[t * chunk + i];
                coarse[t] = ssum;
            }
            __syncthreads();
            if (t == 0) {
                const unsigned target = K_ - aboveCum;
                unsigned run = 0;
                int cb = active - 1;
                for (; cb > 0; --cb) { if (run + coarse[cb] >= target) break; run += coarse[cb]; }
                int bin = cb * chunk + (chunk - 1);
                for (; bin > cb * chunk; --bin) { if (run + hist4k[bin] >= target) break; run += hist4k[bin]; }
                s_boundBin = (unsigned)bin; s_boundCnt = hist4k[bin]; s_aboveAdd = run;
            }
            __syncthreads();
            const unsigned bin = s_boundBin, bcn = s_boundCnt, addAbove = s_aboveAdd;
            __syncthreads();
            aboveCum += addAbove;
            pref = (lv == 0) ? bin : (lv == 1) ? ((pref << 12) | bin) : ((pref << 8) | bin);
            if (aboveCum + bcn <= (unsigned)SORT2 || lv == 2) {
                T32 = (lv == 0) ? (pref << 20) : (lv == 1) ? (pref << 8) : pref;
                break;
            }
        }
        if (t == 0) s_cnt = 0;
        __syncthreads();
        for (int a = t; a < A_; a += NT2) {
            unsigned key = mono_key(sc[(size_t)a * C_]);
            if (key >= T32) {
                unsigned slot = atomicAdd(&s_cnt, 1u);
                if (slot < (unsigned)SORT2)
                    buf[slot] = ((unsigned long long)key << 32) | (unsigned)(~(unsigned)a);
            }
        }
        __syncthreads();
        const unsigned nn = (s_cnt < (unsigned)SORT2) ? s_cnt : (unsigned)SORT2;
        for (int i = (int)nn + t; i < SORT2; i += NT2) buf[i] = 0ull;
        __syncthreads();
    }

    // ---- bitonic sort ss elements, descending ----
    for (unsigned kk = 2; kk <= (unsigned)ss; kk <<= 1) {
        for (unsigned j = kk >> 1; j > 0; j >>= 1) {
            __syncthreads();
            for (int i = t; i < ss; i += NT2) {
                const int ixj = i ^ (int)j;
                if (ixj > i) {
                    const bool up = ((i & kk) == 0);
                    unsigned long long x = buf[i], y = buf[ixj];
                    if ((x < y) == up) { buf[i] = y; buf[ixj] = x; }
                }
            }
        }
    }
    __syncthreads();

    // ---- emit top K ----
    float* vals_out = out;                              // [B, K, C]
    float* boxes_out = out + (size_t)B_ * K_ * C_;      // [B, K, C, 4]
    const float4* bx = (const float4*)(boxes + (size_t)b * A_ * 4);
    for (int kk = t; kk < K_; kk += NT2) {
        const unsigned long long e = buf[kk];
        const unsigned key = (unsigned)(e >> 32);
        const unsigned aidx = ~(unsigned)e;
        const unsigned bitsv = (key & 0x80000000u) ? (key ^ 0x80000000u) : ~key;
        vals_out[((size_t)b * K_ + kk) * C_ + c] = __uint_as_float(bitsv);
        const float4 bb = bx[aidx];
        *(float4*)&boxes_out[(((size_t)b * K_ + kk) * C_ + c) * 4] = bb;
    }
}

// ---------------- legacy single-kernel path (ws too small) ----------------
__global__ __launch_bounds__(NT)
void topk_select_kernel(const float* __restrict__ scores,
                        const float* __restrict__ boxes,
                        float* __restrict__ out) {
    const int blk = blockIdx.x;
    const int b = blk / C_;
    const int c = blk % C_;
    const float* sc = scores + (size_t)b * A_ * C_ + c;
    constexpr int LCAP = 2048;
    __shared__ unsigned hist[4096];
    __shared__ unsigned coarse[NT];
    __shared__ unsigned long long cand[LCAP];
    __shared__ unsigned s_n, s_boundBin, s_boundCnt, s_aboveAdd;
    const int t = threadIdx.x;
    unsigned aboveCum = 0, pref = 0, T32 = 0;
    for (int lv = 0; lv < 3; ++lv) {
        const int shift = (lv == 0) ? 20 : (lv == 1) ? 8 : 0;
        const int nb = (lv == 2) ? 256 : 4096;
        for (int i = t; i < nb; i += NT) hist[i] = 0;
        __syncthreads();
        for (int a = t; a < A_; a += NT) {
            unsigned key = mono_key(sc[(size_t)a * C_]);
            bool ok = (lv == 0) || (lv == 1 ? ((key >> 20) == pref) : ((key >> 8) == pref));
            if (ok) atomicAdd(&hist[(key >> shift) & (nb - 1)], 1u);
        }
        __syncthreads();
        const int chunk = nb / NT;
        {
            unsigned ssum = 0;
            for (int i = 0; i < chunk; ++i) ssum += hist[t * chunk + i];
            coarse[t] = ssum;
        }
        __syncthreads();
        if (t == 0) {
            const unsigned target = K_ - aboveCum;
            unsigned run = 0;
            int cb = NT - 1;
            for (; cb > 0; --cb) { if (run + coarse[cb] >= target) break; run += coarse[cb]; }
            int bin = cb * chunk + (chunk - 1);
            for (; bin > cb * chunk; --bin) { if (run + hist[bin] >= target) break; run += hist[bin]; }
            s_boundBin = (unsigned)bin; s_boundCnt = hist[bin]; s_aboveAdd = run;
        }
        __syncthreads();
        const unsigned bin = s_boundBin, bcn = s_boundCnt, addAbove = s_aboveAdd;
        __syncthreads();
        aboveCum += addAbove;
        pref = (lv == 0) ? bin : (lv == 1) ? ((pref << 12) | bin) : ((pref << 8) | bin);
        if (aboveCum + bcn <= (unsigned)LCAP || lv == 2) {
            T32 = (lv == 0) ? (pref << 20) : (lv == 1) ? (pref << 8) : pref;
            break;
        }
    }
    if (t == 0) s_n = 0;
    __syncthreads();
    for (int a = t; a < A_; a += NT) {
        unsigned key = mono_key(sc[(size_t)a * C_]);
        if (key >= T32) {
            unsigned slot = atomicAdd(&s_n, 1u);
            if (slot < (unsigned)LCAP)
                cand[slot] = ((unsigned long long)key << 32) | (unsigned)(~(unsigned)a);
        }
    }
    __syncthreads();
    const unsigned n = (s_n < (unsigned)LCAP) ? s_n : (unsigned)LCAP;
    for (int i = (int)n + t; i < LCAP; i += NT) cand[i] = 0ull;
    __syncthreads();
    for (unsigned kk = 2; kk <= (unsigned)LCAP; kk <<= 1) {
        for (unsigned j = kk >> 1; j > 0; j >>= 1) {
            __syncthreads();
            for (int i = t; i < LCAP; i += NT) {
                const int ixj = i ^ (int)j;
                if (ixj > i) {
                    const bool up = ((i & kk) == 0);
                    unsigned long long x = cand[i], y = cand[ixj];
                    if ((x < y) == up) { cand[i] = y; cand[ixj] = x; }
                }
            }
        }
    }
    __syncthreads();
    float* vals_out = out;
    float* boxes_out = out + (size_t)B_ * K_ * C_;
    const float4* bx = (const float4*)(boxes + (size_t)b * A_ * 4);
    for (int kk = t; kk < K_; kk += NT) {
        const unsigned long long e = cand[kk];
        const unsigned key = (unsigned)(e >> 32);
        const unsigned aidx = ~(unsigned)e;
        const unsigned bitsv = (key & 0x80000000u) ? (key ^ 0x80000000u) : ~key;
        vals_out[((size_t)b * K_ + kk) * C_ + c] = __uint_as_float(bitsv);
        const float4 bb = bx[aidx];
        *(float4*)&boxes_out[(((size_t)b * K_ + kk) * C_ + c) * 4] = bb;
    }
}

extern "C" void kernel_launch(void* const* d_in, const int* in_sizes, int n_in,
                              void* d_out, int out_size, void* d_ws, size_t ws_size,
                              hipStream_t stream) {
    const float* scores = (const float*)d_in[0];
    const float* boxes  = (const float*)d_in[1];
    float* out = (float*)d_out;

    if (ws_size < WS_NEED) {
        hipLaunchKernelGGL(topk_select_kernel, dim3(B_ * C_), dim3(NT), 0, stream,
                           scores, boxes, out);
        return;
    }

    char* ws = (char*)d_ws;
    unsigned* gcount = (unsigned*)(ws + GCNT_OFF);
    unsigned long long* gcand = (unsigned long long*)(ws + GCAND_OFF);

    hipMemsetAsync(gcount, 0, GCNT_BYTES, stream);
    hipLaunchKernelGGL(stage_kernel, dim3(B_ * S_), dim3(NT), 0, stream,
                       scores, gcount, gcand);
    hipLaunchKernelGGL(sort_emit_kernel, dim3(B_ * C_), dim3(NT2), 0, stream,
                       scores, boxes, gcount, gcand, out);
}